// Round 7
// baseline (120.032 us; speedup 1.0000x reference)
//
#include <hip/hip_runtime.h>
#include <hip/hip_bf16.h>

#define Bn 8
#define Cn 3
#define Tn 32
#define Hn 128
#define Wn 128
#define HWn (Hn * Wn)          // 16384
#define Nn (Tn * HWn)          // 524288 elems per (b,c)
#define EPSn 1e-5f
#define NQ 8                   // 8-way t-split (4 output slices each)

__device__ __forceinline__ float silu_f(float v) {
    // fast silu: rcp intrinsic skips the div fixup sequence (absmax headroom ~200x)
    return v * __builtin_amdgcn_rcpf(1.0f + __expf(-v));
}

// ========== K12: fused spatial 3x3 conv + temporal 7-tap conv + all analytics ==========
// Block = 128 threads = 2 independent waves (2 adjacent rows); wave = one image row,
// 2 px/thread. No LDS, no __syncthreads. 16 blocks/CU x 2 waves = 32 waves/CU (max).
// Vertical halo via direct loads of rows h-1/h/h+1 (L1/L2-hot); horizontal halo via
// __shfl_up/down. t streamed with a 7-deep register ring; t split in 8 quarters.
// Outputs:
//   raw0/raw1[qtr][bc][s]     = partial sum_t wks{0,1}[t]*g    (kv_s contraction)
//   pt0p/pt1p[bc][t][row]     = per-row  sum_s g*wkt{0,1}[s]   (kv_t contraction)
//   ss0p/ss1p[bc][row*NQ+qtr] = per-wave {sum g, sum g^2}      (SwitchNorm stats)
template<int QTR>
__device__ __forceinline__ void k12_body(
    const float* __restrict__ x, const float* __restrict__ wsp,
    const float* __restrict__ bsp, const float* __restrict__ wtp,
    const float* __restrict__ btp, const float* __restrict__ wkt,
    const float* __restrict__ wks,
    float* __restrict__ raw0, float* __restrict__ raw1,
    float* __restrict__ pt0p, float* __restrict__ pt1p,
    float* __restrict__ ss0p, float* __restrict__ ss1p)
{
    constexpr int O0 = QTR * 4;
    constexpr int O1 = O0 + 4;
    constexpr int SLO = (O0 - 3 < 0) ? 0 : (O0 - 3);
    constexpr int SHI = (O1 + 2 > Tn - 1) ? (Tn - 1) : (O1 + 2);

    const int tid = threadIdx.x;
    const int lane = tid & 63;
    const int wave = tid >> 6;
    const int row = blockIdx.x * 2 + wave;   // 0..127
    const int b   = blockIdx.y;              // 0..7
    const int col = lane * 2;

    // uniform weights -> scalar regs
    float wsp_r[27], bsp_r[3], wt_r[21], bt_r[3];
#pragma unroll
    for (int i = 0; i < 27; ++i) wsp_r[i] = wsp[i];
#pragma unroll
    for (int i = 0; i < 3; ++i) bsp_r[i] = bsp[i];
#pragma unroll
    for (int i = 0; i < 21; ++i) wt_r[i] = wtp[i];
#pragma unroll
    for (int i = 0; i < 3; ++i) bt_r[i] = btp[i];

    const float* xb = x + (size_t)b * Nn + (size_t)row * Wn + col;
    const bool upok = row > 0, dnok = row < Hn - 1;

    const float2 k0v = *(const float2*)(wkt + row * Wn + col);
    const float2 k1v = *(const float2*)(wkt + HWn + row * Wn + col);

    float2 ring[7][3];
    float2 a0[3], a1[3];
    float ps[3], pq[3];
#pragma unroll
    for (int c = 0; c < 3; ++c) {
        a0[c] = make_float2(0.f, 0.f); a1[c] = make_float2(0.f, 0.f);
        ps[c] = 0.f; pq[c] = 0.f;
    }

#define LOADS(t, m_, c_, p_) do {                                          \
        const float* xsl_ = xb + (size_t)(t) * HWn;                        \
        m_ = upok ? *(const float2*)(xsl_ - Wn) : make_float2(0.f, 0.f);   \
        c_ = *(const float2*)(xsl_);                                       \
        p_ = dnok ? *(const float2*)(xsl_ + Wn) : make_float2(0.f, 0.f);   \
    } while (0)

    float2 xm, xc, xp, nm, nc, np;
    LOADS(SLO, xm, xc, xp);

#pragma unroll
    for (int tt = SLO; tt <= SHI + 3; ++tt) {
        if (tt + 1 <= SHI) LOADS(tt + 1, nm, nc, np);   // prefetch next slice
        if (tt <= SHI) {
            float xv[3][4];
            {
                float lu, rd;
                lu = __shfl_up(xm.y, 1);  rd = __shfl_down(xm.x, 1);
                xv[0][0] = (lane == 0) ? 0.f : lu; xv[0][1] = xm.x; xv[0][2] = xm.y;
                xv[0][3] = (lane == 63) ? 0.f : rd;
                lu = __shfl_up(xc.y, 1);  rd = __shfl_down(xc.x, 1);
                xv[1][0] = (lane == 0) ? 0.f : lu; xv[1][1] = xc.x; xv[1][2] = xc.y;
                xv[1][3] = (lane == 63) ? 0.f : rd;
                lu = __shfl_up(xp.y, 1);  rd = __shfl_down(xp.x, 1);
                xv[2][0] = (lane == 0) ? 0.f : lu; xv[2][1] = xp.x; xv[2][2] = xp.y;
                xv[2][3] = (lane == 63) ? 0.f : rd;
            }
#pragma unroll
            for (int c = 0; c < 3; ++c) {
                float s0 = bsp_r[c], s1 = bsp_r[c];
#pragma unroll
                for (int i = 0; i < 3; ++i) {
#pragma unroll
                    for (int j = 0; j < 3; ++j) {
                        const float wv = wsp_r[c * 9 + i * 3 + j];
                        s0 += wv * xv[i][j];
                        s1 += wv * xv[i][j + 1];
                    }
                }
                ring[tt % 7][c].x = silu_f(s0);
                ring[tt % 7][c].y = silu_f(s1);
            }
        }
        const int to = tt - 3;
        if (to >= O0 && to < O1) {          // compile-time pruned per unrolled iter
            float g0[3], g1[3];
            const float wk0 = wks[to];      // uniform scalar loads
            const float wk1 = wks[Tn + to];
#pragma unroll
            for (int c = 0; c < 3; ++c) {
                float t0 = bt_r[c], t1 = bt_r[c];
#pragma unroll
                for (int k = 0; k < 7; ++k) {
                    const int ts = to + k - 3;
                    if (ts >= 0 && ts < Tn) {   // compile-time
                        const float wv = wt_r[c * 7 + k];
                        t0 += wv * ring[ts % 7][c].x;
                        t1 += wv * ring[ts % 7][c].y;
                    }
                }
                t0 = silu_f(silu_f(t0)); t1 = silu_f(silu_f(t1));
                g0[c] = t0; g1[c] = t1;
                a0[c].x += wk0 * t0; a0[c].y += wk0 * t1;
                a1[c].x += wk1 * t0; a1[c].y += wk1 * t1;
                ps[c] += t0 + t1;
                pq[c] += t0 * t0 + t1 * t1;
            }
            float pv[6];
#pragma unroll
            for (int c = 0; c < 3; ++c) {
                pv[c * 2 + 0] = k0v.x * g0[c] + k0v.y * g1[c];
                pv[c * 2 + 1] = k1v.x * g0[c] + k1v.y * g1[c];
            }
#pragma unroll
            for (int v = 0; v < 6; ++v) {
                pv[v] += __shfl_xor(pv[v], 1, 64);
                pv[v] += __shfl_xor(pv[v], 2, 64);
                pv[v] += __shfl_xor(pv[v], 4, 64);
            }
            const int j = lane & 7;
            float r = (j == 0) ? pv[0] : (j == 1) ? pv[1] : (j == 2) ? pv[2]
                    : (j == 3) ? pv[3] : (j == 4) ? pv[4] : (j == 5) ? pv[5] : 0.f;
            r += __shfl_xor(r, 8, 64);
            r += __shfl_xor(r, 16, 64);
            r += __shfl_xor(r, 32, 64);
            if (lane < 6) {
                const int c = lane >> 1, v = lane & 1;
                float* dst = v ? pt1p : pt0p;
                dst[((size_t)(b * 3 + c) * Tn + to) * Hn + row] = r;
            }
        }
        xm = nm; xc = nc; xp = np;          // register rotate (unroll makes free)
    }
#undef LOADS

    // --- wave-reduce ps/pq via the same packed trick ---
    float sv[6] = { ps[0], ps[1], ps[2], pq[0], pq[1], pq[2] };
#pragma unroll
    for (int v = 0; v < 6; ++v) {
        sv[v] += __shfl_xor(sv[v], 1, 64);
        sv[v] += __shfl_xor(sv[v], 2, 64);
        sv[v] += __shfl_xor(sv[v], 4, 64);
    }
    {
        const int j = lane & 7;
        float r = (j == 0) ? sv[0] : (j == 1) ? sv[1] : (j == 2) ? sv[2]
                : (j == 3) ? sv[3] : (j == 4) ? sv[4] : (j == 5) ? sv[5] : 0.f;
        r += __shfl_xor(r, 8, 64);
        r += __shfl_xor(r, 16, 64);
        r += __shfl_xor(r, 32, 64);
        if (lane < 3)
            ss0p[(size_t)(b * 3 + lane) * (Hn * NQ) + row * NQ + QTR] = r;
        else if (lane < 6)
            ss1p[(size_t)(b * 3 + lane - 3) * (Hn * NQ) + row * NQ + QTR] = r;
    }
    // --- raw kv_s stores (per-quarter buffers) ---
#pragma unroll
    for (int c = 0; c < 3; ++c) {
        const size_t off = (size_t)(QTR * 24 + b * 3 + c) * HWn + (size_t)row * Wn + col;
        *(float2*)(raw0 + off) = a0[c];
        *(float2*)(raw1 + off) = a1[c];
    }
}

__global__ __launch_bounds__(128, 8) void k12_conv(
    const float* __restrict__ x, const float* __restrict__ wsp,
    const float* __restrict__ bsp, const float* __restrict__ wtp,
    const float* __restrict__ btp, const float* __restrict__ wkt,
    const float* __restrict__ wks,
    float* __restrict__ raw0, float* __restrict__ raw1,
    float* __restrict__ pt0p, float* __restrict__ pt1p,
    float* __restrict__ ss0p, float* __restrict__ ss1p)
{
    switch (blockIdx.z) {
    case 0: k12_body<0>(x, wsp, bsp, wtp, btp, wkt, wks, raw0, raw1, pt0p, pt1p, ss0p, ss1p); break;
    case 1: k12_body<1>(x, wsp, bsp, wtp, btp, wkt, wks, raw0, raw1, pt0p, pt1p, ss0p, ss1p); break;
    case 2: k12_body<2>(x, wsp, bsp, wtp, btp, wkt, wks, raw0, raw1, pt0p, pt1p, ss0p, ss1p); break;
    case 3: k12_body<3>(x, wsp, bsp, wtp, btp, wkt, wks, raw0, raw1, pt0p, pt1p, ss0p, ss1p); break;
    case 4: k12_body<4>(x, wsp, bsp, wtp, btp, wkt, wks, raw0, raw1, pt0p, pt1p, ss0p, ss1p); break;
    case 5: k12_body<5>(x, wsp, bsp, wtp, btp, wkt, wks, raw0, raw1, pt0p, pt1p, ss0p, ss1p); break;
    case 6: k12_body<6>(x, wsp, bsp, wtp, btp, wkt, wks, raw0, raw1, pt0p, pt1p, ss0p, ss1p); break;
    default: k12_body<7>(x, wsp, bsp, wtp, btp, wkt, wks, raw0, raw1, pt0p, pt1p, ss0p, ss1p); break;
    }
}

// ========== K3a: parallel reduction of pt/ss partials + wkt/wks sums ==========
// blocks 0..23: per-bc reduce; block 24: weight sums.
__global__ __launch_bounds__(256) void k3a_reduce(
    const float* __restrict__ pt0p, const float* __restrict__ pt1p,
    const float* __restrict__ ss0p, const float* __restrict__ ss1p,
    const float* __restrict__ wkt, const float* __restrict__ wks,
    float* __restrict__ kvt0r, float* __restrict__ kvt1r,
    float* __restrict__ ssS, float* __restrict__ ssSS, float* __restrict__ wsum)
{
    const int blk = blockIdx.x;
    const int tid = threadIdx.x;
    if (blk < Bn * Cn) {
        // pt reduce: 32 t-rows of 128; 8 threads per t
        const int t = tid >> 3, g = tid & 7;
        const float4* p0 = (const float4*)(pt0p + ((size_t)blk * Tn + t) * Hn) + g * 4;
        const float4* p1 = (const float4*)(pt1p + ((size_t)blk * Tn + t) * Hn) + g * 4;
        float4 A0 = p0[0], A1 = p0[1], A2 = p0[2], A3 = p0[3];
        float4 B0 = p1[0], B1 = p1[1], B2 = p1[2], B3 = p1[3];
        float s0 = ((A0.x + A0.y) + (A0.z + A0.w)) + ((A1.x + A1.y) + (A1.z + A1.w))
                 + ((A2.x + A2.y) + (A2.z + A2.w)) + ((A3.x + A3.y) + (A3.z + A3.w));
        float s1 = ((B0.x + B0.y) + (B0.z + B0.w)) + ((B1.x + B1.y) + (B1.z + B1.w))
                 + ((B2.x + B2.y) + (B2.z + B2.w)) + ((B3.x + B3.y) + (B3.z + B3.w));
        s0 += __shfl_xor(s0, 1, 64); s0 += __shfl_xor(s0, 2, 64); s0 += __shfl_xor(s0, 4, 64);
        s1 += __shfl_xor(s1, 1, 64); s1 += __shfl_xor(s1, 2, 64); s1 += __shfl_xor(s1, 4, 64);
        if (g == 0) { kvt0r[blk * Tn + t] = s0; kvt1r[blk * Tn + t] = s1; }
        // ss reduce: 1024 floats each array
        const float4* q0 = (const float4*)(ss0p + (size_t)blk * (Hn * NQ));
        const float4* q1 = (const float4*)(ss1p + (size_t)blk * (Hn * NQ));
        float4 a4 = q0[tid], b4 = q1[tid];
        float a = (a4.x + a4.y) + (a4.z + a4.w);
        float bb = (b4.x + b4.y) + (b4.z + b4.w);
        __shared__ float r0[256], r1[256];
        r0[tid] = a; r1[tid] = bb;
        __syncthreads();
        for (int off = 128; off > 0; off >>= 1) {
            if (tid < off) { r0[tid] += r0[tid + off]; r1[tid] += r1[tid + off]; }
            __syncthreads();
        }
        if (tid == 0) { ssS[blk] = r0[0]; ssSS[blk] = r1[0]; }
    } else {
        // wkt sums (2 x 16384) and wks sums (2 x 32)
        const float4* w0 = (const float4*)wkt;
        const float4* w1 = (const float4*)(wkt + HWn);
        float l0 = 0.f, l1 = 0.f;
        for (int i = tid; i < HWn / 4; i += 256) {
            float4 t0 = w0[i], t1 = w1[i];
            l0 += (t0.x + t0.y) + (t0.z + t0.w);
            l1 += (t1.x + t1.y) + (t1.z + t1.w);
        }
        __shared__ float r0[256], r1[256];
        r0[tid] = l0; r1[tid] = l1;
        __syncthreads();
        for (int off = 128; off > 0; off >>= 1) {
            if (tid < off) { r0[tid] += r0[tid + off]; r1[tid] += r1[tid + off]; }
            __syncthreads();
        }
        if (tid == 0) { wsum[0] = r0[0]; wsum[1] = r1[0]; }
        if (tid < 64) {
            float v = wks[tid];   // lanes 0..31 hold wks0, 32..63 hold wks1
            v += __shfl_xor(v, 1, 64); v += __shfl_xor(v, 2, 64);
            v += __shfl_xor(v, 4, 64); v += __shfl_xor(v, 8, 64);
            v += __shfl_xor(v, 16, 64);
            if (tid == 0) wsum[2] = v;
            if (tid == 32) wsum[3] = v;
        }
    }
}

// ========== K3b: SwitchNorm stats + kv_t softmax -> A, scale/shift (tiny) ==========
__global__ __launch_bounds__(256) void k3b_finalize(
    const float* __restrict__ kvt0r, const float* __restrict__ kvt1r,
    const float* __restrict__ ssS, const float* __restrict__ ssSS,
    const float* __restrict__ mean_w, const float* __restrict__ var_w,
    const float* __restrict__ snw, const float* __restrict__ snb,
    const float* __restrict__ wsum,
    float* __restrict__ scale, float* __restrict__ shift, float* __restrict__ A)
{
    const int tid = threadIdx.x;
    __shared__ float kvt0[Bn * Cn * Tn], kvt1[Bn * Cn * Tn];
    __shared__ float sW[4];
    for (int i = tid; i < Bn * Cn * Tn; i += 256) { kvt0[i] = kvt0r[i]; kvt1[i] = kvt1r[i]; }
    if (tid < 4) sW[tid] = wsum[tid];
    __shared__ float sh_mean[24], sh_var[24], sh_temp[24];
    __shared__ float sh_mln[8], sh_vln[8], sh_mbn[3], sh_vbn[3];
    __shared__ float sh_mw[3], sh_vw[3];
    __shared__ float sh_scale[24], sh_shift[24];
    if (tid < 24) {
        float S = ssS[tid], SS = ssSS[tid];
        const float Nf = (float)Nn;
        float mean = S / Nf;
        float var = (SS - S * mean) / (Nf - 1.0f);   // unbiased (ddof=1)
        sh_mean[tid] = mean; sh_var[tid] = var; sh_temp[tid] = var + mean * mean;
    }
    __syncthreads();
    if (tid == 0) {
        for (int b = 0; b < Bn; ++b) {
            float m = 0.f, tp = 0.f;
            for (int c = 0; c < Cn; ++c) { m += sh_mean[b * 3 + c]; tp += sh_temp[b * 3 + c]; }
            m *= (1.0f / 3.0f); tp *= (1.0f / 3.0f);
            sh_mln[b] = m; sh_vln[b] = tp - m * m;
        }
        for (int c = 0; c < Cn; ++c) {
            float m = 0.f, tp = 0.f;
            for (int b = 0; b < Bn; ++b) { m += sh_mean[b * 3 + c]; tp += sh_temp[b * 3 + c]; }
            m *= 0.125f; tp *= 0.125f;
            sh_mbn[c] = m; sh_vbn[c] = tp - m * m;
        }
        {
            float m0 = mean_w[0], m1 = mean_w[1], m2 = mean_w[2];
            float mm = fmaxf(m0, fmaxf(m1, m2));
            float e0 = __expf(m0 - mm), e1 = __expf(m1 - mm), e2 = __expf(m2 - mm);
            float inv = 1.0f / (e0 + e1 + e2);
            sh_mw[0] = e0 * inv; sh_mw[1] = e1 * inv; sh_mw[2] = e2 * inv;
        }
        {
            float v0 = var_w[0], v1 = var_w[1], v2 = var_w[2];
            float vm = fmaxf(v0, fmaxf(v1, v2));
            float e0 = __expf(v0 - vm), e1 = __expf(v1 - vm), e2 = __expf(v2 - vm);
            float inv = 1.0f / (e0 + e1 + e2);
            sh_vw[0] = e0 * inv; sh_vw[1] = e1 * inv; sh_vw[2] = e2 * inv;
        }
    }
    __syncthreads();
    if (tid < 24) {
        int b = tid / 3, c = tid % 3;
        float mean = sh_mw[0] * sh_mean[tid] + sh_mw[1] * sh_mln[b] + sh_mw[2] * sh_mbn[c];
        float var  = sh_vw[0] * sh_var[tid]  + sh_vw[1] * sh_vln[b] + sh_vw[2] * sh_vbn[c];
        float inv = 1.0f / sqrtf(var + EPSn);
        float sc = inv * snw[c];
        float sf = snb[c] - mean * sc;
        sh_scale[tid] = sc; sh_shift[tid] = sf;
        scale[tid] = sc; shift[tid] = sf;
    }
    __syncthreads();
    for (int i = tid; i < Bn * Cn * Tn; i += 256) {
        int bc = i >> 5;
        kvt0[i] = sh_scale[bc] * kvt0[i] + sh_shift[bc] * sW[0];
        kvt1[i] = sh_scale[bc] * kvt1[i] + sh_shift[bc] * sW[1];
    }
    __syncthreads();
    if (tid < 24) {
        float m = -3.4e38f;
        for (int t = 0; t < Tn; ++t) m = fmaxf(m, kvt0[tid * Tn + t]);
        float se = 0.f;
        for (int t = 0; t < Tn; ++t) se += __expf(kvt0[tid * Tn + t] - m);
        float inv = 1.0f / se;
        for (int t = 0; t < Tn; ++t)
            A[tid * Tn + t] = sqrtf(__expf(kvt0[tid * Tn + t] - m) * inv) * kvt1[tid * Tn + t];
    }
}

// ========== K5a: reduce raw quarters + affine; chunk max/expsum -> v0s/v1s, ms ==========
__global__ __launch_bounds__(256) void k5a_maxsum(
    const float* __restrict__ raw0, const float* __restrict__ raw1,
    const float* __restrict__ scale, const float* __restrict__ shift,
    const float* __restrict__ wsum, float* __restrict__ v0s,
    float* __restrict__ v1s, float2* __restrict__ ms)
{
    const int ch = blockIdx.x;   // 0..7 (chunks of 2048)
    const int bc = blockIdx.y;   // 0..23
    const int tid = threadIdx.x, lane = tid & 63, wave = tid >> 6;
    const float sc = scale[bc], sf = shift[bc];
    const float c0 = sf * wsum[2], c1 = sf * wsum[3];
    const size_t idx = (size_t)bc * HWn + ch * 2048 + tid * 8;
    float4 r0a = make_float4(0.f, 0.f, 0.f, 0.f), r0b = r0a, r1a = r0a, r1b = r0a;
#pragma unroll
    for (int q = 0; q < NQ; ++q) {
        const float* p0 = raw0 + (size_t)q * 24 * HWn + idx;
        const float* p1 = raw1 + (size_t)q * 24 * HWn + idx;
        float4 t0 = ((const float4*)p0)[0], t1 = ((const float4*)p0)[1];
        float4 u0 = ((const float4*)p1)[0], u1 = ((const float4*)p1)[1];
        r0a.x += t0.x; r0a.y += t0.y; r0a.z += t0.z; r0a.w += t0.w;
        r0b.x += t1.x; r0b.y += t1.y; r0b.z += t1.z; r0b.w += t1.w;
        r1a.x += u0.x; r1a.y += u0.y; r1a.z += u0.z; r1a.w += u0.w;
        r1b.x += u1.x; r1b.y += u1.y; r1b.z += u1.z; r1b.w += u1.w;
    }
    float v0[8] = { sc * r0a.x + c0, sc * r0a.y + c0, sc * r0a.z + c0, sc * r0a.w + c0,
                    sc * r0b.x + c0, sc * r0b.y + c0, sc * r0b.z + c0, sc * r0b.w + c0 };
    float v1[8] = { sc * r1a.x + c1, sc * r1a.y + c1, sc * r1a.z + c1, sc * r1a.w + c1,
                    sc * r1b.x + c1, sc * r1b.y + c1, sc * r1b.z + c1, sc * r1b.w + c1 };
    ((float4*)(v0s + idx))[0] = make_float4(v0[0], v0[1], v0[2], v0[3]);
    ((float4*)(v0s + idx))[1] = make_float4(v0[4], v0[5], v0[6], v0[7]);
    ((float4*)(v1s + idx))[0] = make_float4(v1[0], v1[1], v1[2], v1[3]);
    ((float4*)(v1s + idx))[1] = make_float4(v1[4], v1[5], v1[6], v1[7]);
    float m = -3.4e38f;
#pragma unroll
    for (int i = 0; i < 8; ++i) m = fmaxf(m, v0[i]);
#pragma unroll
    for (int d = 1; d < 64; d <<= 1) m = fmaxf(m, __shfl_xor(m, d, 64));
    __shared__ float wm[4], wsm[4];
    if (lane == 0) wm[wave] = m;
    __syncthreads();
    const float M = fmaxf(fmaxf(wm[0], wm[1]), fmaxf(wm[2], wm[3]));
    float s = 0.f;
#pragma unroll
    for (int i = 0; i < 8; ++i) s += __expf(v0[i] - M);
#pragma unroll
    for (int d = 1; d < 64; d <<= 1) s += __shfl_xor(s, d, 64);
    if (lane == 0) wsm[wave] = s;
    __syncthreads();
    if (tid == 0) {
        float2 o; o.x = M; o.y = wsm[0] + wsm[1] + wsm[2] + wsm[3];
        ms[bc * 8 + ch] = o;
    }
}

// ========== K6: B finalize inline + outer product out[bc,t,s] = A[t]*B[s] ==========
__global__ __launch_bounds__(256) void k6_outer(
    const float* __restrict__ v0s, const float* __restrict__ v1s,
    const float2* __restrict__ ms, const float* __restrict__ A,
    float* __restrict__ out)
{
    const int ch = blockIdx.x;   // 0..15 (chunks of 1024)
    const int bc = blockIdx.y;   // 0..23
    const int tid = threadIdx.x;
    __shared__ float a[Tn];
    if (tid < Tn) a[tid] = A[bc * Tn + tid];
    float M = -3.4e38f;
#pragma unroll
    for (int j = 0; j < 8; ++j) M = fmaxf(M, ms[bc * 8 + j].x);
    float S = 0.f;
#pragma unroll
    for (int j = 0; j < 8; ++j) S += ms[bc * 8 + j].y * __expf(ms[bc * 8 + j].x - M);
    const float invS = __builtin_amdgcn_rcpf(S);
    const int s = ch * 1024 + tid * 4;
    float4 r0 = *(const float4*)(v0s + (size_t)bc * HWn + s);
    float4 r1 = *(const float4*)(v1s + (size_t)bc * HWn + s);
    float4 Bv;
    Bv.x = sqrtf(__expf(r0.x - M) * invS) * r1.x;
    Bv.y = sqrtf(__expf(r0.y - M) * invS) * r1.y;
    Bv.z = sqrtf(__expf(r0.z - M) * invS) * r1.z;
    Bv.w = sqrtf(__expf(r0.w - M) * invS) * r1.w;
    __syncthreads();
    float* op = out + (size_t)bc * Nn + s;
#pragma unroll
    for (int t = 0; t < Tn; ++t) {
        const float av = a[t];
        float4 o; o.x = av * Bv.x; o.y = av * Bv.y; o.z = av * Bv.z; o.w = av * Bv.w;
        *(float4*)(op + (size_t)t * HWn) = o;
    }
}

extern "C" void kernel_launch(void* const* d_in, const int* in_sizes, int n_in,
                              void* d_out, int out_size, void* d_ws, size_t ws_size,
                              hipStream_t stream) {
    const float* x          = (const float*)d_in[0];
    const float* w_spatial  = (const float*)d_in[1];
    const float* b_spatial  = (const float*)d_in[2];
    const float* w_temporal = (const float*)d_in[3];
    const float* b_temporal = (const float*)d_in[4];
    const float* sn_weight  = (const float*)d_in[5];
    const float* sn_bias    = (const float*)d_in[6];
    const float* mean_weight= (const float*)d_in[7];
    const float* var_weight = (const float*)d_in[8];
    const float* w_kv_s     = (const float*)d_in[9];
    const float* w_kv_t     = (const float*)d_in[10];
    float* out = (float*)d_out;
    float* ws  = (float*)d_ws;

    // ws layout (floats)
    float* raw0  = ws;                                   // [NQ][24][HWn] = 3145728
    float* raw1  = raw0 + (size_t)NQ * Bn * Cn * HWn;    // 3145728
    float* pt0p  = raw1 + (size_t)NQ * Bn * Cn * HWn;    // 24*32*128 = 98304
    float* pt1p  = pt0p + (size_t)Bn * Cn * Tn * Hn;     // 98304
    float* ss0p  = pt1p + (size_t)Bn * Cn * Tn * Hn;     // 24*1024 = 24576
    float* ss1p  = ss0p + (size_t)Bn * Cn * Hn * NQ;     // 24576
    float* v0s   = ss1p + (size_t)Bn * Cn * Hn * NQ;     // 24*HWn = 393216
    float* v1s   = v0s + (size_t)Bn * Cn * HWn;          // 393216
    float* kvt0r = v1s + (size_t)Bn * Cn * HWn;          // 768
    float* kvt1r = kvt0r + Bn * Cn * Tn;                 // 768
    float* ssS   = kvt1r + Bn * Cn * Tn;                 // 24
    float* ssSS  = ssS + 24;                             // 24
    float* scale = ssSS + 24;                            // 24
    float* shift = scale + 24;                           // 24
    float* A     = shift + 24;                           // 768
    float* wsum  = A + Bn * Cn * Tn;                     // 4
    float2* ms   = (float2*)(wsum + 4);                  // 192 float2

    k12_conv<<<dim3(Hn / 2, Bn, NQ), 128, 0, stream>>>(x, w_spatial, b_spatial,
                                                       w_temporal, b_temporal,
                                                       w_kv_t, w_kv_s,
                                                       raw0, raw1, pt0p, pt1p, ss0p, ss1p);
    k3a_reduce<<<Bn * Cn + 1, 256, 0, stream>>>(pt0p, pt1p, ss0p, ss1p, w_kv_t, w_kv_s,
                                                kvt0r, kvt1r, ssS, ssSS, wsum);
    k3b_finalize<<<1, 256, 0, stream>>>(kvt0r, kvt1r, ssS, ssSS,
                                        mean_weight, var_weight, sn_weight, sn_bias,
                                        wsum, scale, shift, A);
    k5a_maxsum<<<dim3(8, Bn * Cn), 256, 0, stream>>>(raw0, raw1, scale, shift, wsum,
                                                     v0s, v1s, ms);
    k6_outer<<<dim3(16, Bn * Cn), 256, 0, stream>>>(v0s, v1s, ms, A, out);
}

// Round 8
// 73.360 us; speedup vs baseline: 1.6362x; 1.6362x over previous
//
#include <hip/hip_runtime.h>
#include <hip/hip_bf16.h>

#define Bn 8
#define Cn 3
#define Tn 32
#define Hn 128
#define Wn 128
#define HWn (Hn * Wn)          // 16384
#define Nn (Tn * HWn)          // 524288 elems per (b,c)
#define EPSn 1e-5f
#define NQ 8                   // 8-way t-split (4 output slices each)

__device__ __forceinline__ float silu_f(float v) {
    // fast silu: rcp intrinsic skips the div fixup sequence (absmax headroom ~200x)
    return v * __builtin_amdgcn_rcpf(1.0f + __expf(-v));
}

// ========== K12: fused spatial 3x3 conv + temporal 7-tap conv + all analytics ==========
// Block = 128 threads = 2 independent waves (2 adjacent rows); wave = one image row,
// 2 px/thread. No LDS, no __syncthreads. 16 blocks/CU x 2 waves = 32 waves/CU (max).
// NOTE: launch_bounds must NOT request a min-occupancy — (128,8) capped VGPR at 32 and
// spilled the register ring to scratch (FETCH/WRITE ballooned to 173/199 MB, 2x slower).
// Vertical halo via direct loads of rows h-1/h/h+1 (L1/L2-hot); horizontal halo via
// __shfl_up/down. t streamed with a 7-deep register ring; t split in 8 quarters.
// Outputs:
//   raw0/raw1[qtr][bc][s]     = partial sum_t wks{0,1}[t]*g    (kv_s contraction)
//   pt0p/pt1p[bc][t][row]     = per-row  sum_s g*wkt{0,1}[s]   (kv_t contraction)
//   ss0p/ss1p[bc][row*NQ+qtr] = per-wave {sum g, sum g^2}      (SwitchNorm stats)
template<int QTR>
__device__ __forceinline__ void k12_body(
    const float* __restrict__ x, const float* __restrict__ wsp,
    const float* __restrict__ bsp, const float* __restrict__ wtp,
    const float* __restrict__ btp, const float* __restrict__ wkt,
    const float* __restrict__ wks,
    float* __restrict__ raw0, float* __restrict__ raw1,
    float* __restrict__ pt0p, float* __restrict__ pt1p,
    float* __restrict__ ss0p, float* __restrict__ ss1p)
{
    constexpr int O0 = QTR * 4;
    constexpr int O1 = O0 + 4;
    constexpr int SLO = (O0 - 3 < 0) ? 0 : (O0 - 3);
    constexpr int SHI = (O1 + 2 > Tn - 1) ? (Tn - 1) : (O1 + 2);

    const int tid = threadIdx.x;
    const int lane = tid & 63;
    const int wave = tid >> 6;
    const int row = blockIdx.x * 2 + wave;   // 0..127
    const int b   = blockIdx.y;              // 0..7
    const int col = lane * 2;

    // uniform weights -> scalar regs
    float wsp_r[27], bsp_r[3], wt_r[21], bt_r[3];
#pragma unroll
    for (int i = 0; i < 27; ++i) wsp_r[i] = wsp[i];
#pragma unroll
    for (int i = 0; i < 3; ++i) bsp_r[i] = bsp[i];
#pragma unroll
    for (int i = 0; i < 21; ++i) wt_r[i] = wtp[i];
#pragma unroll
    for (int i = 0; i < 3; ++i) bt_r[i] = btp[i];

    const float* xb = x + (size_t)b * Nn + (size_t)row * Wn + col;
    const bool upok = row > 0, dnok = row < Hn - 1;

    const float2 k0v = *(const float2*)(wkt + row * Wn + col);
    const float2 k1v = *(const float2*)(wkt + HWn + row * Wn + col);

    float2 ring[7][3];
    float2 a0[3], a1[3];
    float ps[3], pq[3];
#pragma unroll
    for (int c = 0; c < 3; ++c) {
        a0[c] = make_float2(0.f, 0.f); a1[c] = make_float2(0.f, 0.f);
        ps[c] = 0.f; pq[c] = 0.f;
    }

#define LOADS(t, m_, c_, p_) do {                                          \
        const float* xsl_ = xb + (size_t)(t) * HWn;                        \
        m_ = upok ? *(const float2*)(xsl_ - Wn) : make_float2(0.f, 0.f);   \
        c_ = *(const float2*)(xsl_);                                       \
        p_ = dnok ? *(const float2*)(xsl_ + Wn) : make_float2(0.f, 0.f);   \
    } while (0)

    float2 xm, xc, xp, nm, nc, np;
    LOADS(SLO, xm, xc, xp);

#pragma unroll
    for (int tt = SLO; tt <= SHI + 3; ++tt) {
        if (tt + 1 <= SHI) LOADS(tt + 1, nm, nc, np);   // prefetch next slice
        if (tt <= SHI) {
            float xv[3][4];
            {
                float lu, rd;
                lu = __shfl_up(xm.y, 1);  rd = __shfl_down(xm.x, 1);
                xv[0][0] = (lane == 0) ? 0.f : lu; xv[0][1] = xm.x; xv[0][2] = xm.y;
                xv[0][3] = (lane == 63) ? 0.f : rd;
                lu = __shfl_up(xc.y, 1);  rd = __shfl_down(xc.x, 1);
                xv[1][0] = (lane == 0) ? 0.f : lu; xv[1][1] = xc.x; xv[1][2] = xc.y;
                xv[1][3] = (lane == 63) ? 0.f : rd;
                lu = __shfl_up(xp.y, 1);  rd = __shfl_down(xp.x, 1);
                xv[2][0] = (lane == 0) ? 0.f : lu; xv[2][1] = xp.x; xv[2][2] = xp.y;
                xv[2][3] = (lane == 63) ? 0.f : rd;
            }
#pragma unroll
            for (int c = 0; c < 3; ++c) {
                float s0 = bsp_r[c], s1 = bsp_r[c];
#pragma unroll
                for (int i = 0; i < 3; ++i) {
#pragma unroll
                    for (int j = 0; j < 3; ++j) {
                        const float wv = wsp_r[c * 9 + i * 3 + j];
                        s0 += wv * xv[i][j];
                        s1 += wv * xv[i][j + 1];
                    }
                }
                ring[tt % 7][c].x = silu_f(s0);
                ring[tt % 7][c].y = silu_f(s1);
            }
        }
        const int to = tt - 3;
        if (to >= O0 && to < O1) {          // compile-time pruned per unrolled iter
            float g0[3], g1[3];
            const float wk0 = wks[to];      // uniform scalar loads
            const float wk1 = wks[Tn + to];
#pragma unroll
            for (int c = 0; c < 3; ++c) {
                float t0 = bt_r[c], t1 = bt_r[c];
#pragma unroll
                for (int k = 0; k < 7; ++k) {
                    const int ts = to + k - 3;
                    if (ts >= 0 && ts < Tn) {   // compile-time
                        const float wv = wt_r[c * 7 + k];
                        t0 += wv * ring[ts % 7][c].x;
                        t1 += wv * ring[ts % 7][c].y;
                    }
                }
                t0 = silu_f(silu_f(t0)); t1 = silu_f(silu_f(t1));
                g0[c] = t0; g1[c] = t1;
                a0[c].x += wk0 * t0; a0[c].y += wk0 * t1;
                a1[c].x += wk1 * t0; a1[c].y += wk1 * t1;
                ps[c] += t0 + t1;
                pq[c] += t0 * t0 + t1 * t1;
            }
            float pv[6];
#pragma unroll
            for (int c = 0; c < 3; ++c) {
                pv[c * 2 + 0] = k0v.x * g0[c] + k0v.y * g1[c];
                pv[c * 2 + 1] = k1v.x * g0[c] + k1v.y * g1[c];
            }
#pragma unroll
            for (int v = 0; v < 6; ++v) {
                pv[v] += __shfl_xor(pv[v], 1, 64);
                pv[v] += __shfl_xor(pv[v], 2, 64);
                pv[v] += __shfl_xor(pv[v], 4, 64);
            }
            const int j = lane & 7;
            float r = (j == 0) ? pv[0] : (j == 1) ? pv[1] : (j == 2) ? pv[2]
                    : (j == 3) ? pv[3] : (j == 4) ? pv[4] : (j == 5) ? pv[5] : 0.f;
            r += __shfl_xor(r, 8, 64);
            r += __shfl_xor(r, 16, 64);
            r += __shfl_xor(r, 32, 64);
            if (lane < 6) {
                const int c = lane >> 1, v = lane & 1;
                float* dst = v ? pt1p : pt0p;
                dst[((size_t)(b * 3 + c) * Tn + to) * Hn + row] = r;
            }
        }
        xm = nm; xc = nc; xp = np;          // register rotate (unroll makes free)
    }
#undef LOADS

    // --- wave-reduce ps/pq via the same packed trick ---
    float sv[6] = { ps[0], ps[1], ps[2], pq[0], pq[1], pq[2] };
#pragma unroll
    for (int v = 0; v < 6; ++v) {
        sv[v] += __shfl_xor(sv[v], 1, 64);
        sv[v] += __shfl_xor(sv[v], 2, 64);
        sv[v] += __shfl_xor(sv[v], 4, 64);
    }
    {
        const int j = lane & 7;
        float r = (j == 0) ? sv[0] : (j == 1) ? sv[1] : (j == 2) ? sv[2]
                : (j == 3) ? sv[3] : (j == 4) ? sv[4] : (j == 5) ? sv[5] : 0.f;
        r += __shfl_xor(r, 8, 64);
        r += __shfl_xor(r, 16, 64);
        r += __shfl_xor(r, 32, 64);
        if (lane < 3)
            ss0p[(size_t)(b * 3 + lane) * (Hn * NQ) + row * NQ + QTR] = r;
        else if (lane < 6)
            ss1p[(size_t)(b * 3 + lane - 3) * (Hn * NQ) + row * NQ + QTR] = r;
    }
    // --- raw kv_s stores (per-quarter buffers) ---
#pragma unroll
    for (int c = 0; c < 3; ++c) {
        const size_t off = (size_t)(QTR * 24 + b * 3 + c) * HWn + (size_t)row * Wn + col;
        *(float2*)(raw0 + off) = a0[c];
        *(float2*)(raw1 + off) = a1[c];
    }
}

__global__ __launch_bounds__(128) void k12_conv(
    const float* __restrict__ x, const float* __restrict__ wsp,
    const float* __restrict__ bsp, const float* __restrict__ wtp,
    const float* __restrict__ btp, const float* __restrict__ wkt,
    const float* __restrict__ wks,
    float* __restrict__ raw0, float* __restrict__ raw1,
    float* __restrict__ pt0p, float* __restrict__ pt1p,
    float* __restrict__ ss0p, float* __restrict__ ss1p)
{
    switch (blockIdx.z) {
    case 0: k12_body<0>(x, wsp, bsp, wtp, btp, wkt, wks, raw0, raw1, pt0p, pt1p, ss0p, ss1p); break;
    case 1: k12_body<1>(x, wsp, bsp, wtp, btp, wkt, wks, raw0, raw1, pt0p, pt1p, ss0p, ss1p); break;
    case 2: k12_body<2>(x, wsp, bsp, wtp, btp, wkt, wks, raw0, raw1, pt0p, pt1p, ss0p, ss1p); break;
    case 3: k12_body<3>(x, wsp, bsp, wtp, btp, wkt, wks, raw0, raw1, pt0p, pt1p, ss0p, ss1p); break;
    case 4: k12_body<4>(x, wsp, bsp, wtp, btp, wkt, wks, raw0, raw1, pt0p, pt1p, ss0p, ss1p); break;
    case 5: k12_body<5>(x, wsp, bsp, wtp, btp, wkt, wks, raw0, raw1, pt0p, pt1p, ss0p, ss1p); break;
    case 6: k12_body<6>(x, wsp, bsp, wtp, btp, wkt, wks, raw0, raw1, pt0p, pt1p, ss0p, ss1p); break;
    default: k12_body<7>(x, wsp, bsp, wtp, btp, wkt, wks, raw0, raw1, pt0p, pt1p, ss0p, ss1p); break;
    }
}

// ========== K3a: parallel reduction of pt/ss partials + wkt/wks sums ==========
// blocks 0..23: per-bc reduce; block 24: weight sums.
__global__ __launch_bounds__(256) void k3a_reduce(
    const float* __restrict__ pt0p, const float* __restrict__ pt1p,
    const float* __restrict__ ss0p, const float* __restrict__ ss1p,
    const float* __restrict__ wkt, const float* __restrict__ wks,
    float* __restrict__ kvt0r, float* __restrict__ kvt1r,
    float* __restrict__ ssS, float* __restrict__ ssSS, float* __restrict__ wsum)
{
    const int blk = blockIdx.x;
    const int tid = threadIdx.x;
    if (blk < Bn * Cn) {
        // pt reduce: 32 t-rows of 128; 8 threads per t
        const int t = tid >> 3, g = tid & 7;
        const float4* p0 = (const float4*)(pt0p + ((size_t)blk * Tn + t) * Hn) + g * 4;
        const float4* p1 = (const float4*)(pt1p + ((size_t)blk * Tn + t) * Hn) + g * 4;
        float4 A0 = p0[0], A1 = p0[1], A2 = p0[2], A3 = p0[3];
        float4 B0 = p1[0], B1 = p1[1], B2 = p1[2], B3 = p1[3];
        float s0 = ((A0.x + A0.y) + (A0.z + A0.w)) + ((A1.x + A1.y) + (A1.z + A1.w))
                 + ((A2.x + A2.y) + (A2.z + A2.w)) + ((A3.x + A3.y) + (A3.z + A3.w));
        float s1 = ((B0.x + B0.y) + (B0.z + B0.w)) + ((B1.x + B1.y) + (B1.z + B1.w))
                 + ((B2.x + B2.y) + (B2.z + B2.w)) + ((B3.x + B3.y) + (B3.z + B3.w));
        s0 += __shfl_xor(s0, 1, 64); s0 += __shfl_xor(s0, 2, 64); s0 += __shfl_xor(s0, 4, 64);
        s1 += __shfl_xor(s1, 1, 64); s1 += __shfl_xor(s1, 2, 64); s1 += __shfl_xor(s1, 4, 64);
        if (g == 0) { kvt0r[blk * Tn + t] = s0; kvt1r[blk * Tn + t] = s1; }
        // ss reduce: 1024 floats each array
        const float4* q0 = (const float4*)(ss0p + (size_t)blk * (Hn * NQ));
        const float4* q1 = (const float4*)(ss1p + (size_t)blk * (Hn * NQ));
        float4 a4 = q0[tid], b4 = q1[tid];
        float a = (a4.x + a4.y) + (a4.z + a4.w);
        float bb = (b4.x + b4.y) + (b4.z + b4.w);
        __shared__ float r0[256], r1[256];
        r0[tid] = a; r1[tid] = bb;
        __syncthreads();
        for (int off = 128; off > 0; off >>= 1) {
            if (tid < off) { r0[tid] += r0[tid + off]; r1[tid] += r1[tid + off]; }
            __syncthreads();
        }
        if (tid == 0) { ssS[blk] = r0[0]; ssSS[blk] = r1[0]; }
    } else {
        // wkt sums (2 x 16384) and wks sums (2 x 32)
        const float4* w0 = (const float4*)wkt;
        const float4* w1 = (const float4*)(wkt + HWn);
        float l0 = 0.f, l1 = 0.f;
        for (int i = tid; i < HWn / 4; i += 256) {
            float4 t0 = w0[i], t1 = w1[i];
            l0 += (t0.x + t0.y) + (t0.z + t0.w);
            l1 += (t1.x + t1.y) + (t1.z + t1.w);
        }
        __shared__ float r0[256], r1[256];
        r0[tid] = l0; r1[tid] = l1;
        __syncthreads();
        for (int off = 128; off > 0; off >>= 1) {
            if (tid < off) { r0[tid] += r0[tid + off]; r1[tid] += r1[tid + off]; }
            __syncthreads();
        }
        if (tid == 0) { wsum[0] = r0[0]; wsum[1] = r1[0]; }
        if (tid < 64) {
            float v = wks[tid];   // lanes 0..31 hold wks0, 32..63 hold wks1
            v += __shfl_xor(v, 1, 64); v += __shfl_xor(v, 2, 64);
            v += __shfl_xor(v, 4, 64); v += __shfl_xor(v, 8, 64);
            v += __shfl_xor(v, 16, 64);
            if (tid == 0) wsum[2] = v;
            if (tid == 32) wsum[3] = v;
        }
    }
}

// ========== K3b: SwitchNorm stats + kv_t softmax -> A, scale/shift (tiny) ==========
__global__ __launch_bounds__(256) void k3b_finalize(
    const float* __restrict__ kvt0r, const float* __restrict__ kvt1r,
    const float* __restrict__ ssS, const float* __restrict__ ssSS,
    const float* __restrict__ mean_w, const float* __restrict__ var_w,
    const float* __restrict__ snw, const float* __restrict__ snb,
    const float* __restrict__ wsum,
    float* __restrict__ scale, float* __restrict__ shift, float* __restrict__ A)
{
    const int tid = threadIdx.x;
    __shared__ float kvt0[Bn * Cn * Tn], kvt1[Bn * Cn * Tn];
    __shared__ float sW[4];
    for (int i = tid; i < Bn * Cn * Tn; i += 256) { kvt0[i] = kvt0r[i]; kvt1[i] = kvt1r[i]; }
    if (tid < 4) sW[tid] = wsum[tid];
    __shared__ float sh_mean[24], sh_var[24], sh_temp[24];
    __shared__ float sh_mln[8], sh_vln[8], sh_mbn[3], sh_vbn[3];
    __shared__ float sh_mw[3], sh_vw[3];
    __shared__ float sh_scale[24], sh_shift[24];
    if (tid < 24) {
        float S = ssS[tid], SS = ssSS[tid];
        const float Nf = (float)Nn;
        float mean = S / Nf;
        float var = (SS - S * mean) / (Nf - 1.0f);   // unbiased (ddof=1)
        sh_mean[tid] = mean; sh_var[tid] = var; sh_temp[tid] = var + mean * mean;
    }
    __syncthreads();
    if (tid == 0) {
        for (int b = 0; b < Bn; ++b) {
            float m = 0.f, tp = 0.f;
            for (int c = 0; c < Cn; ++c) { m += sh_mean[b * 3 + c]; tp += sh_temp[b * 3 + c]; }
            m *= (1.0f / 3.0f); tp *= (1.0f / 3.0f);
            sh_mln[b] = m; sh_vln[b] = tp - m * m;
        }
        for (int c = 0; c < Cn; ++c) {
            float m = 0.f, tp = 0.f;
            for (int b = 0; b < Bn; ++b) { m += sh_mean[b * 3 + c]; tp += sh_temp[b * 3 + c]; }
            m *= 0.125f; tp *= 0.125f;
            sh_mbn[c] = m; sh_vbn[c] = tp - m * m;
        }
        {
            float m0 = mean_w[0], m1 = mean_w[1], m2 = mean_w[2];
            float mm = fmaxf(m0, fmaxf(m1, m2));
            float e0 = __expf(m0 - mm), e1 = __expf(m1 - mm), e2 = __expf(m2 - mm);
            float inv = 1.0f / (e0 + e1 + e2);
            sh_mw[0] = e0 * inv; sh_mw[1] = e1 * inv; sh_mw[2] = e2 * inv;
        }
        {
            float v0 = var_w[0], v1 = var_w[1], v2 = var_w[2];
            float vm = fmaxf(v0, fmaxf(v1, v2));
            float e0 = __expf(v0 - vm), e1 = __expf(v1 - vm), e2 = __expf(v2 - vm);
            float inv = 1.0f / (e0 + e1 + e2);
            sh_vw[0] = e0 * inv; sh_vw[1] = e1 * inv; sh_vw[2] = e2 * inv;
        }
    }
    __syncthreads();
    if (tid < 24) {
        int b = tid / 3, c = tid % 3;
        float mean = sh_mw[0] * sh_mean[tid] + sh_mw[1] * sh_mln[b] + sh_mw[2] * sh_mbn[c];
        float var  = sh_vw[0] * sh_var[tid]  + sh_vw[1] * sh_vln[b] + sh_vw[2] * sh_vbn[c];
        float inv = 1.0f / sqrtf(var + EPSn);
        float sc = inv * snw[c];
        float sf = snb[c] - mean * sc;
        sh_scale[tid] = sc; sh_shift[tid] = sf;
        scale[tid] = sc; shift[tid] = sf;
    }
    __syncthreads();
    for (int i = tid; i < Bn * Cn * Tn; i += 256) {
        int bc = i >> 5;
        kvt0[i] = sh_scale[bc] * kvt0[i] + sh_shift[bc] * sW[0];
        kvt1[i] = sh_scale[bc] * kvt1[i] + sh_shift[bc] * sW[1];
    }
    __syncthreads();
    if (tid < 24) {
        float m = -3.4e38f;
        for (int t = 0; t < Tn; ++t) m = fmaxf(m, kvt0[tid * Tn + t]);
        float se = 0.f;
        for (int t = 0; t < Tn; ++t) se += __expf(kvt0[tid * Tn + t] - m);
        float inv = 1.0f / se;
        for (int t = 0; t < Tn; ++t)
            A[tid * Tn + t] = sqrtf(__expf(kvt0[tid * Tn + t] - m) * inv) * kvt1[tid * Tn + t];
    }
}

// ========== K5a: reduce raw quarters + affine; chunk max/expsum -> v0s/v1s, ms ==========
__global__ __launch_bounds__(256) void k5a_maxsum(
    const float* __restrict__ raw0, const float* __restrict__ raw1,
    const float* __restrict__ scale, const float* __restrict__ shift,
    const float* __restrict__ wsum, float* __restrict__ v0s,
    float* __restrict__ v1s, float2* __restrict__ ms)
{
    const int ch = blockIdx.x;   // 0..7 (chunks of 2048)
    const int bc = blockIdx.y;   // 0..23
    const int tid = threadIdx.x, lane = tid & 63, wave = tid >> 6;
    const float sc = scale[bc], sf = shift[bc];
    const float c0 = sf * wsum[2], c1 = sf * wsum[3];
    const size_t idx = (size_t)bc * HWn + ch * 2048 + tid * 8;
    float4 r0a = make_float4(0.f, 0.f, 0.f, 0.f), r0b = r0a, r1a = r0a, r1b = r0a;
#pragma unroll
    for (int q = 0; q < NQ; ++q) {
        const float* p0 = raw0 + (size_t)q * 24 * HWn + idx;
        const float* p1 = raw1 + (size_t)q * 24 * HWn + idx;
        float4 t0 = ((const float4*)p0)[0], t1 = ((const float4*)p0)[1];
        float4 u0 = ((const float4*)p1)[0], u1 = ((const float4*)p1)[1];
        r0a.x += t0.x; r0a.y += t0.y; r0a.z += t0.z; r0a.w += t0.w;
        r0b.x += t1.x; r0b.y += t1.y; r0b.z += t1.z; r0b.w += t1.w;
        r1a.x += u0.x; r1a.y += u0.y; r1a.z += u0.z; r1a.w += u0.w;
        r1b.x += u1.x; r1b.y += u1.y; r1b.z += u1.z; r1b.w += u1.w;
    }
    float v0[8] = { sc * r0a.x + c0, sc * r0a.y + c0, sc * r0a.z + c0, sc * r0a.w + c0,
                    sc * r0b.x + c0, sc * r0b.y + c0, sc * r0b.z + c0, sc * r0b.w + c0 };
    float v1[8] = { sc * r1a.x + c1, sc * r1a.y + c1, sc * r1a.z + c1, sc * r1a.w + c1,
                    sc * r1b.x + c1, sc * r1b.y + c1, sc * r1b.z + c1, sc * r1b.w + c1 };
    ((float4*)(v0s + idx))[0] = make_float4(v0[0], v0[1], v0[2], v0[3]);
    ((float4*)(v0s + idx))[1] = make_float4(v0[4], v0[5], v0[6], v0[7]);
    ((float4*)(v1s + idx))[0] = make_float4(v1[0], v1[1], v1[2], v1[3]);
    ((float4*)(v1s + idx))[1] = make_float4(v1[4], v1[5], v1[6], v1[7]);
    float m = -3.4e38f;
#pragma unroll
    for (int i = 0; i < 8; ++i) m = fmaxf(m, v0[i]);
#pragma unroll
    for (int d = 1; d < 64; d <<= 1) m = fmaxf(m, __shfl_xor(m, d, 64));
    __shared__ float wm[4], wsm[4];
    if (lane == 0) wm[wave] = m;
    __syncthreads();
    const float M = fmaxf(fmaxf(wm[0], wm[1]), fmaxf(wm[2], wm[3]));
    float s = 0.f;
#pragma unroll
    for (int i = 0; i < 8; ++i) s += __expf(v0[i] - M);
#pragma unroll
    for (int d = 1; d < 64; d <<= 1) s += __shfl_xor(s, d, 64);
    if (lane == 0) wsm[wave] = s;
    __syncthreads();
    if (tid == 0) {
        float2 o; o.x = M; o.y = wsm[0] + wsm[1] + wsm[2] + wsm[3];
        ms[bc * 8 + ch] = o;
    }
}

// ========== K6: B finalize inline + outer product out[bc,t,s] = A[t]*B[s] ==========
__global__ __launch_bounds__(256) void k6_outer(
    const float* __restrict__ v0s, const float* __restrict__ v1s,
    const float2* __restrict__ ms, const float* __restrict__ A,
    float* __restrict__ out)
{
    const int ch = blockIdx.x;   // 0..15 (chunks of 1024)
    const int bc = blockIdx.y;   // 0..23
    const int tid = threadIdx.x;
    __shared__ float a[Tn];
    if (tid < Tn) a[tid] = A[bc * Tn + tid];
    float M = -3.4e38f;
#pragma unroll
    for (int j = 0; j < 8; ++j) M = fmaxf(M, ms[bc * 8 + j].x);
    float S = 0.f;
#pragma unroll
    for (int j = 0; j < 8; ++j) S += ms[bc * 8 + j].y * __expf(ms[bc * 8 + j].x - M);
    const float invS = __builtin_amdgcn_rcpf(S);
    const int s = ch * 1024 + tid * 4;
    float4 r0 = *(const float4*)(v0s + (size_t)bc * HWn + s);
    float4 r1 = *(const float4*)(v1s + (size_t)bc * HWn + s);
    float4 Bv;
    Bv.x = sqrtf(__expf(r0.x - M) * invS) * r1.x;
    Bv.y = sqrtf(__expf(r0.y - M) * invS) * r1.y;
    Bv.z = sqrtf(__expf(r0.z - M) * invS) * r1.z;
    Bv.w = sqrtf(__expf(r0.w - M) * invS) * r1.w;
    __syncthreads();
    float* op = out + (size_t)bc * Nn + s;
#pragma unroll
    for (int t = 0; t < Tn; ++t) {
        const float av = a[t];
        float4 o; o.x = av * Bv.x; o.y = av * Bv.y; o.z = av * Bv.z; o.w = av * Bv.w;
        *(float4*)(op + (size_t)t * HWn) = o;
    }
}

extern "C" void kernel_launch(void* const* d_in, const int* in_sizes, int n_in,
                              void* d_out, int out_size, void* d_ws, size_t ws_size,
                              hipStream_t stream) {
    const float* x          = (const float*)d_in[0];
    const float* w_spatial  = (const float*)d_in[1];
    const float* b_spatial  = (const float*)d_in[2];
    const float* w_temporal = (const float*)d_in[3];
    const float* b_temporal = (const float*)d_in[4];
    const float* sn_weight  = (const float*)d_in[5];
    const float* sn_bias    = (const float*)d_in[6];
    const float* mean_weight= (const float*)d_in[7];
    const float* var_weight = (const float*)d_in[8];
    const float* w_kv_s     = (const float*)d_in[9];
    const float* w_kv_t     = (const float*)d_in[10];
    float* out = (float*)d_out;
    float* ws  = (float*)d_ws;

    // ws layout (floats)
    float* raw0  = ws;                                   // [NQ][24][HWn] = 3145728
    float* raw1  = raw0 + (size_t)NQ * Bn * Cn * HWn;    // 3145728
    float* pt0p  = raw1 + (size_t)NQ * Bn * Cn * HWn;    // 24*32*128 = 98304
    float* pt1p  = pt0p + (size_t)Bn * Cn * Tn * Hn;     // 98304
    float* ss0p  = pt1p + (size_t)Bn * Cn * Tn * Hn;     // 24*1024 = 24576
    float* ss1p  = ss0p + (size_t)Bn * Cn * Hn * NQ;     // 24576
    float* v0s   = ss1p + (size_t)Bn * Cn * Hn * NQ;     // 24*HWn = 393216
    float* v1s   = v0s + (size_t)Bn * Cn * HWn;          // 393216
    float* kvt0r = v1s + (size_t)Bn * Cn * HWn;          // 768
    float* kvt1r = kvt0r + Bn * Cn * Tn;                 // 768
    float* ssS   = kvt1r + Bn * Cn * Tn;                 // 24
    float* ssSS  = ssS + 24;                             // 24
    float* scale = ssSS + 24;                            // 24
    float* shift = scale + 24;                           // 24
    float* A     = shift + 24;                           // 768
    float* wsum  = A + Bn * Cn * Tn;                     // 4
    float2* ms   = (float2*)(wsum + 4);                  // 192 float2

    k12_conv<<<dim3(Hn / 2, Bn, NQ), 128, 0, stream>>>(x, w_spatial, b_spatial,
                                                       w_temporal, b_temporal,
                                                       w_kv_t, w_kv_s,
                                                       raw0, raw1, pt0p, pt1p, ss0p, ss1p);
    k3a_reduce<<<Bn * Cn + 1, 256, 0, stream>>>(pt0p, pt1p, ss0p, ss1p, w_kv_t, w_kv_s,
                                                kvt0r, kvt1r, ssS, ssSS, wsum);
    k3b_finalize<<<1, 256, 0, stream>>>(kvt0r, kvt1r, ssS, ssSS,
                                        mean_weight, var_weight, sn_weight, sn_bias,
                                        wsum, scale, shift, A);
    k5a_maxsum<<<dim3(8, Bn * Cn), 256, 0, stream>>>(raw0, raw1, scale, shift, wsum,
                                                     v0s, v1s, ms);
    k6_outer<<<dim3(16, Bn * Cn), 256, 0, stream>>>(v0s, v1s, ms, A, out);
}

// Round 9
// 72.391 us; speedup vs baseline: 1.6581x; 1.0134x over previous
//
#include <hip/hip_runtime.h>
#include <hip/hip_bf16.h>

#define Bn 8
#define Cn 3
#define Tn 32
#define Hn 128
#define Wn 128
#define HWn (Hn * Wn)          // 16384
#define Nn (Tn * HWn)          // 524288 elems per (b,c)
#define EPSn 1e-5f
#define NQ 8                   // 8-way t-split (4 output slices each)

__device__ __forceinline__ float silu_f(float v) {
    // fast silu: rcp intrinsic skips the div fixup sequence (absmax headroom ~200x)
    return v * __builtin_amdgcn_rcpf(1.0f + __expf(-v));
}

// ========== K12: fused spatial 3x3 conv + temporal 7-tap conv + all analytics ==========
// Block = 128 threads = 2 independent waves (2 adjacent rows); wave = one image row,
// 2 px/thread. No LDS, no __syncthreads.
// REGISTER BUDGET IS THE LEVER: VGPR must be <= 64 (waves/SIMD halve above 64 — m69).
// Round-7 lesson: (128,8) capped VGPR at 32 -> spilled ring to scratch (350 MB traffic).
// Round-8 lesson: VGPR=68 (4 over the cliff) -> only 2 waves/SIMD, VALUBusy 52%.
// So: no software prefetch temporaries (compiler hoists within budget) + (128,4).
// Vertical halo via direct loads of rows h-1/h/h+1 (L1/L2-hot); horizontal halo via
// __shfl_up/down. t streamed with a 7-deep register ring; t split in 8 quarters.
// Outputs:
//   raw0/raw1[qtr][bc][s]     = partial sum_t wks{0,1}[t]*g    (kv_s contraction)
//   pt0p/pt1p[bc][t][row]     = per-row  sum_s g*wkt{0,1}[s]   (kv_t contraction)
//   ss0p/ss1p[bc][row*NQ+qtr] = per-wave {sum g, sum g^2}      (SwitchNorm stats)
template<int QTR>
__device__ __forceinline__ void k12_body(
    const float* __restrict__ x, const float* __restrict__ wsp,
    const float* __restrict__ bsp, const float* __restrict__ wtp,
    const float* __restrict__ btp, const float* __restrict__ wkt,
    const float* __restrict__ wks,
    float* __restrict__ raw0, float* __restrict__ raw1,
    float* __restrict__ pt0p, float* __restrict__ pt1p,
    float* __restrict__ ss0p, float* __restrict__ ss1p)
{
    constexpr int O0 = QTR * 4;
    constexpr int O1 = O0 + 4;
    constexpr int SLO = (O0 - 3 < 0) ? 0 : (O0 - 3);
    constexpr int SHI = (O1 + 2 > Tn - 1) ? (Tn - 1) : (O1 + 2);

    const int tid = threadIdx.x;
    const int lane = tid & 63;
    const int wave = tid >> 6;
    const int row = blockIdx.x * 2 + wave;   // 0..127
    const int b   = blockIdx.y;              // 0..7
    const int col = lane * 2;

    // uniform weights -> scalar regs
    float wsp_r[27], bsp_r[3], wt_r[21], bt_r[3];
#pragma unroll
    for (int i = 0; i < 27; ++i) wsp_r[i] = wsp[i];
#pragma unroll
    for (int i = 0; i < 3; ++i) bsp_r[i] = bsp[i];
#pragma unroll
    for (int i = 0; i < 21; ++i) wt_r[i] = wtp[i];
#pragma unroll
    for (int i = 0; i < 3; ++i) bt_r[i] = btp[i];

    const float* xb = x + (size_t)b * Nn + (size_t)row * Wn + col;
    const bool upok = row > 0, dnok = row < Hn - 1;

    const float2 k0v = *(const float2*)(wkt + row * Wn + col);
    const float2 k1v = *(const float2*)(wkt + HWn + row * Wn + col);

    float2 ring[7][3];
    float2 a0[3], a1[3];
    float ps[3], pq[3];
#pragma unroll
    for (int c = 0; c < 3; ++c) {
        a0[c] = make_float2(0.f, 0.f); a1[c] = make_float2(0.f, 0.f);
        ps[c] = 0.f; pq[c] = 0.f;
    }

#pragma unroll
    for (int tt = SLO; tt <= SHI + 3; ++tt) {
        if (tt <= SHI) {
            const float* xsl = xb + (size_t)tt * HWn;
            float2 xm = upok ? *(const float2*)(xsl - Wn) : make_float2(0.f, 0.f);
            float2 xc = *(const float2*)(xsl);
            float2 xp = dnok ? *(const float2*)(xsl + Wn) : make_float2(0.f, 0.f);
            float xv[3][4];
            {
                float lu, rd;
                lu = __shfl_up(xm.y, 1);  rd = __shfl_down(xm.x, 1);
                xv[0][0] = (lane == 0) ? 0.f : lu; xv[0][1] = xm.x; xv[0][2] = xm.y;
                xv[0][3] = (lane == 63) ? 0.f : rd;
                lu = __shfl_up(xc.y, 1);  rd = __shfl_down(xc.x, 1);
                xv[1][0] = (lane == 0) ? 0.f : lu; xv[1][1] = xc.x; xv[1][2] = xc.y;
                xv[1][3] = (lane == 63) ? 0.f : rd;
                lu = __shfl_up(xp.y, 1);  rd = __shfl_down(xp.x, 1);
                xv[2][0] = (lane == 0) ? 0.f : lu; xv[2][1] = xp.x; xv[2][2] = xp.y;
                xv[2][3] = (lane == 63) ? 0.f : rd;
            }
#pragma unroll
            for (int c = 0; c < 3; ++c) {
                float s0 = bsp_r[c], s1 = bsp_r[c];
#pragma unroll
                for (int i = 0; i < 3; ++i) {
#pragma unroll
                    for (int j = 0; j < 3; ++j) {
                        const float wv = wsp_r[c * 9 + i * 3 + j];
                        s0 += wv * xv[i][j];
                        s1 += wv * xv[i][j + 1];
                    }
                }
                ring[tt % 7][c].x = silu_f(s0);
                ring[tt % 7][c].y = silu_f(s1);
            }
        }
        const int to = tt - 3;
        if (to >= O0 && to < O1) {          // compile-time pruned per unrolled iter
            float g0[3], g1[3];
            const float wk0 = wks[to];      // uniform scalar loads
            const float wk1 = wks[Tn + to];
#pragma unroll
            for (int c = 0; c < 3; ++c) {
                float t0 = bt_r[c], t1 = bt_r[c];
#pragma unroll
                for (int k = 0; k < 7; ++k) {
                    const int ts = to + k - 3;
                    if (ts >= 0 && ts < Tn) {   // compile-time
                        const float wv = wt_r[c * 7 + k];
                        t0 += wv * ring[ts % 7][c].x;
                        t1 += wv * ring[ts % 7][c].y;
                    }
                }
                t0 = silu_f(silu_f(t0)); t1 = silu_f(silu_f(t1));
                g0[c] = t0; g1[c] = t1;
                a0[c].x += wk0 * t0; a0[c].y += wk0 * t1;
                a1[c].x += wk1 * t0; a1[c].y += wk1 * t1;
                ps[c] += t0 + t1;
                pq[c] += t0 * t0 + t1 * t1;
            }
            float pv[6];
#pragma unroll
            for (int c = 0; c < 3; ++c) {
                pv[c * 2 + 0] = k0v.x * g0[c] + k0v.y * g1[c];
                pv[c * 2 + 1] = k1v.x * g0[c] + k1v.y * g1[c];
            }
#pragma unroll
            for (int v = 0; v < 6; ++v) {
                pv[v] += __shfl_xor(pv[v], 1, 64);
                pv[v] += __shfl_xor(pv[v], 2, 64);
                pv[v] += __shfl_xor(pv[v], 4, 64);
            }
            const int j = lane & 7;
            float r = (j == 0) ? pv[0] : (j == 1) ? pv[1] : (j == 2) ? pv[2]
                    : (j == 3) ? pv[3] : (j == 4) ? pv[4] : (j == 5) ? pv[5] : 0.f;
            r += __shfl_xor(r, 8, 64);
            r += __shfl_xor(r, 16, 64);
            r += __shfl_xor(r, 32, 64);
            if (lane < 6) {
                const int c = lane >> 1, v = lane & 1;
                float* dst = v ? pt1p : pt0p;
                dst[((size_t)(b * 3 + c) * Tn + to) * Hn + row] = r;
            }
        }
    }

    // --- wave-reduce ps/pq via the same packed trick ---
    float sv[6] = { ps[0], ps[1], ps[2], pq[0], pq[1], pq[2] };
#pragma unroll
    for (int v = 0; v < 6; ++v) {
        sv[v] += __shfl_xor(sv[v], 1, 64);
        sv[v] += __shfl_xor(sv[v], 2, 64);
        sv[v] += __shfl_xor(sv[v], 4, 64);
    }
    {
        const int j = lane & 7;
        float r = (j == 0) ? sv[0] : (j == 1) ? sv[1] : (j == 2) ? sv[2]
                : (j == 3) ? sv[3] : (j == 4) ? sv[4] : (j == 5) ? sv[5] : 0.f;
        r += __shfl_xor(r, 8, 64);
        r += __shfl_xor(r, 16, 64);
        r += __shfl_xor(r, 32, 64);
        if (lane < 3)
            ss0p[(size_t)(b * 3 + lane) * (Hn * NQ) + row * NQ + QTR] = r;
        else if (lane < 6)
            ss1p[(size_t)(b * 3 + lane - 3) * (Hn * NQ) + row * NQ + QTR] = r;
    }
    // --- raw kv_s stores (per-quarter buffers) ---
#pragma unroll
    for (int c = 0; c < 3; ++c) {
        const size_t off = (size_t)(QTR * 24 + b * 3 + c) * HWn + (size_t)row * Wn + col;
        *(float2*)(raw0 + off) = a0[c];
        *(float2*)(raw1 + off) = a1[c];
    }
}

__global__ __launch_bounds__(128, 4) void k12_conv(
    const float* __restrict__ x, const float* __restrict__ wsp,
    const float* __restrict__ bsp, const float* __restrict__ wtp,
    const float* __restrict__ btp, const float* __restrict__ wkt,
    const float* __restrict__ wks,
    float* __restrict__ raw0, float* __restrict__ raw1,
    float* __restrict__ pt0p, float* __restrict__ pt1p,
    float* __restrict__ ss0p, float* __restrict__ ss1p)
{
    switch (blockIdx.z) {
    case 0: k12_body<0>(x, wsp, bsp, wtp, btp, wkt, wks, raw0, raw1, pt0p, pt1p, ss0p, ss1p); break;
    case 1: k12_body<1>(x, wsp, bsp, wtp, btp, wkt, wks, raw0, raw1, pt0p, pt1p, ss0p, ss1p); break;
    case 2: k12_body<2>(x, wsp, bsp, wtp, btp, wkt, wks, raw0, raw1, pt0p, pt1p, ss0p, ss1p); break;
    case 3: k12_body<3>(x, wsp, bsp, wtp, btp, wkt, wks, raw0, raw1, pt0p, pt1p, ss0p, ss1p); break;
    case 4: k12_body<4>(x, wsp, bsp, wtp, btp, wkt, wks, raw0, raw1, pt0p, pt1p, ss0p, ss1p); break;
    case 5: k12_body<5>(x, wsp, bsp, wtp, btp, wkt, wks, raw0, raw1, pt0p, pt1p, ss0p, ss1p); break;
    case 6: k12_body<6>(x, wsp, bsp, wtp, btp, wkt, wks, raw0, raw1, pt0p, pt1p, ss0p, ss1p); break;
    default: k12_body<7>(x, wsp, bsp, wtp, btp, wkt, wks, raw0, raw1, pt0p, pt1p, ss0p, ss1p); break;
    }
}

// ========== K3a: parallel reduction of pt/ss partials + wkt/wks sums ==========
// blocks 0..23: per-bc reduce; block 24: weight sums.
__global__ __launch_bounds__(256) void k3a_reduce(
    const float* __restrict__ pt0p, const float* __restrict__ pt1p,
    const float* __restrict__ ss0p, const float* __restrict__ ss1p,
    const float* __restrict__ wkt, const float* __restrict__ wks,
    float* __restrict__ kvt0r, float* __restrict__ kvt1r,
    float* __restrict__ ssS, float* __restrict__ ssSS, float* __restrict__ wsum)
{
    const int blk = blockIdx.x;
    const int tid = threadIdx.x;
    if (blk < Bn * Cn) {
        // pt reduce: 32 t-rows of 128; 8 threads per t
        const int t = tid >> 3, g = tid & 7;
        const float4* p0 = (const float4*)(pt0p + ((size_t)blk * Tn + t) * Hn) + g * 4;
        const float4* p1 = (const float4*)(pt1p + ((size_t)blk * Tn + t) * Hn) + g * 4;
        float4 A0 = p0[0], A1 = p0[1], A2 = p0[2], A3 = p0[3];
        float4 B0 = p1[0], B1 = p1[1], B2 = p1[2], B3 = p1[3];
        float s0 = ((A0.x + A0.y) + (A0.z + A0.w)) + ((A1.x + A1.y) + (A1.z + A1.w))
                 + ((A2.x + A2.y) + (A2.z + A2.w)) + ((A3.x + A3.y) + (A3.z + A3.w));
        float s1 = ((B0.x + B0.y) + (B0.z + B0.w)) + ((B1.x + B1.y) + (B1.z + B1.w))
                 + ((B2.x + B2.y) + (B2.z + B2.w)) + ((B3.x + B3.y) + (B3.z + B3.w));
        s0 += __shfl_xor(s0, 1, 64); s0 += __shfl_xor(s0, 2, 64); s0 += __shfl_xor(s0, 4, 64);
        s1 += __shfl_xor(s1, 1, 64); s1 += __shfl_xor(s1, 2, 64); s1 += __shfl_xor(s1, 4, 64);
        if (g == 0) { kvt0r[blk * Tn + t] = s0; kvt1r[blk * Tn + t] = s1; }
        // ss reduce: 1024 floats each array
        const float4* q0 = (const float4*)(ss0p + (size_t)blk * (Hn * NQ));
        const float4* q1 = (const float4*)(ss1p + (size_t)blk * (Hn * NQ));
        float4 a4 = q0[tid], b4 = q1[tid];
        float a = (a4.x + a4.y) + (a4.z + a4.w);
        float bb = (b4.x + b4.y) + (b4.z + b4.w);
        __shared__ float r0[256], r1[256];
        r0[tid] = a; r1[tid] = bb;
        __syncthreads();
        for (int off = 128; off > 0; off >>= 1) {
            if (tid < off) { r0[tid] += r0[tid + off]; r1[tid] += r1[tid + off]; }
            __syncthreads();
        }
        if (tid == 0) { ssS[blk] = r0[0]; ssSS[blk] = r1[0]; }
    } else {
        // wkt sums (2 x 16384) and wks sums (2 x 32)
        const float4* w0 = (const float4*)wkt;
        const float4* w1 = (const float4*)(wkt + HWn);
        float l0 = 0.f, l1 = 0.f;
        for (int i = tid; i < HWn / 4; i += 256) {
            float4 t0 = w0[i], t1 = w1[i];
            l0 += (t0.x + t0.y) + (t0.z + t0.w);
            l1 += (t1.x + t1.y) + (t1.z + t1.w);
        }
        __shared__ float r0[256], r1[256];
        r0[tid] = l0; r1[tid] = l1;
        __syncthreads();
        for (int off = 128; off > 0; off >>= 1) {
            if (tid < off) { r0[tid] += r0[tid + off]; r1[tid] += r1[tid + off]; }
            __syncthreads();
        }
        if (tid == 0) { wsum[0] = r0[0]; wsum[1] = r1[0]; }
        if (tid < 64) {
            float v = wks[tid];   // lanes 0..31 hold wks0, 32..63 hold wks1
            v += __shfl_xor(v, 1, 64); v += __shfl_xor(v, 2, 64);
            v += __shfl_xor(v, 4, 64); v += __shfl_xor(v, 8, 64);
            v += __shfl_xor(v, 16, 64);
            if (tid == 0) wsum[2] = v;
            if (tid == 32) wsum[3] = v;
        }
    }
}

// ========== K3b: SwitchNorm stats + kv_t softmax -> A, scale/shift (tiny) ==========
__global__ __launch_bounds__(256) void k3b_finalize(
    const float* __restrict__ kvt0r, const float* __restrict__ kvt1r,
    const float* __restrict__ ssS, const float* __restrict__ ssSS,
    const float* __restrict__ mean_w, const float* __restrict__ var_w,
    const float* __restrict__ snw, const float* __restrict__ snb,
    const float* __restrict__ wsum,
    float* __restrict__ scale, float* __restrict__ shift, float* __restrict__ A)
{
    const int tid = threadIdx.x;
    __shared__ float kvt0[Bn * Cn * Tn], kvt1[Bn * Cn * Tn];
    __shared__ float sW[4];
    for (int i = tid; i < Bn * Cn * Tn; i += 256) { kvt0[i] = kvt0r[i]; kvt1[i] = kvt1r[i]; }
    if (tid < 4) sW[tid] = wsum[tid];
    __shared__ float sh_mean[24], sh_var[24], sh_temp[24];
    __shared__ float sh_mln[8], sh_vln[8], sh_mbn[3], sh_vbn[3];
    __shared__ float sh_mw[3], sh_vw[3];
    __shared__ float sh_scale[24], sh_shift[24];
    if (tid < 24) {
        float S = ssS[tid], SS = ssSS[tid];
        const float Nf = (float)Nn;
        float mean = S / Nf;
        float var = (SS - S * mean) / (Nf - 1.0f);   // unbiased (ddof=1)
        sh_mean[tid] = mean; sh_var[tid] = var; sh_temp[tid] = var + mean * mean;
    }
    __syncthreads();
    if (tid == 0) {
        for (int b = 0; b < Bn; ++b) {
            float m = 0.f, tp = 0.f;
            for (int c = 0; c < Cn; ++c) { m += sh_mean[b * 3 + c]; tp += sh_temp[b * 3 + c]; }
            m *= (1.0f / 3.0f); tp *= (1.0f / 3.0f);
            sh_mln[b] = m; sh_vln[b] = tp - m * m;
        }
        for (int c = 0; c < Cn; ++c) {
            float m = 0.f, tp = 0.f;
            for (int b = 0; b < Bn; ++b) { m += sh_mean[b * 3 + c]; tp += sh_temp[b * 3 + c]; }
            m *= 0.125f; tp *= 0.125f;
            sh_mbn[c] = m; sh_vbn[c] = tp - m * m;
        }
        {
            float m0 = mean_w[0], m1 = mean_w[1], m2 = mean_w[2];
            float mm = fmaxf(m0, fmaxf(m1, m2));
            float e0 = __expf(m0 - mm), e1 = __expf(m1 - mm), e2 = __expf(m2 - mm);
            float inv = 1.0f / (e0 + e1 + e2);
            sh_mw[0] = e0 * inv; sh_mw[1] = e1 * inv; sh_mw[2] = e2 * inv;
        }
        {
            float v0 = var_w[0], v1 = var_w[1], v2 = var_w[2];
            float vm = fmaxf(v0, fmaxf(v1, v2));
            float e0 = __expf(v0 - vm), e1 = __expf(v1 - vm), e2 = __expf(v2 - vm);
            float inv = 1.0f / (e0 + e1 + e2);
            sh_vw[0] = e0 * inv; sh_vw[1] = e1 * inv; sh_vw[2] = e2 * inv;
        }
    }
    __syncthreads();
    if (tid < 24) {
        int b = tid / 3, c = tid % 3;
        float mean = sh_mw[0] * sh_mean[tid] + sh_mw[1] * sh_mln[b] + sh_mw[2] * sh_mbn[c];
        float var  = sh_vw[0] * sh_var[tid]  + sh_vw[1] * sh_vln[b] + sh_vw[2] * sh_vbn[c];
        float inv = 1.0f / sqrtf(var + EPSn);
        float sc = inv * snw[c];
        float sf = snb[c] - mean * sc;
        sh_scale[tid] = sc; sh_shift[tid] = sf;
        scale[tid] = sc; shift[tid] = sf;
    }
    __syncthreads();
    for (int i = tid; i < Bn * Cn * Tn; i += 256) {
        int bc = i >> 5;
        kvt0[i] = sh_scale[bc] * kvt0[i] + sh_shift[bc] * sW[0];
        kvt1[i] = sh_scale[bc] * kvt1[i] + sh_shift[bc] * sW[1];
    }
    __syncthreads();
    if (tid < 24) {
        float m = -3.4e38f;
        for (int t = 0; t < Tn; ++t) m = fmaxf(m, kvt0[tid * Tn + t]);
        float se = 0.f;
        for (int t = 0; t < Tn; ++t) se += __expf(kvt0[tid * Tn + t] - m);
        float inv = 1.0f / se;
        for (int t = 0; t < Tn; ++t)
            A[tid * Tn + t] = sqrtf(__expf(kvt0[tid * Tn + t] - m) * inv) * kvt1[tid * Tn + t];
    }
}

// ========== K5a: reduce raw quarters + affine; chunk max/expsum -> v0s/v1s, ms ==========
__global__ __launch_bounds__(256) void k5a_maxsum(
    const float* __restrict__ raw0, const float* __restrict__ raw1,
    const float* __restrict__ scale, const float* __restrict__ shift,
    const float* __restrict__ wsum, float* __restrict__ v0s,
    float* __restrict__ v1s, float2* __restrict__ ms)
{
    const int ch = blockIdx.x;   // 0..7 (chunks of 2048)
    const int bc = blockIdx.y;   // 0..23
    const int tid = threadIdx.x, lane = tid & 63, wave = tid >> 6;
    const float sc = scale[bc], sf = shift[bc];
    const float c0 = sf * wsum[2], c1 = sf * wsum[3];
    const size_t idx = (size_t)bc * HWn + ch * 2048 + tid * 8;
    float4 r0a = make_float4(0.f, 0.f, 0.f, 0.f), r0b = r0a, r1a = r0a, r1b = r0a;
#pragma unroll
    for (int q = 0; q < NQ; ++q) {
        const float* p0 = raw0 + (size_t)q * 24 * HWn + idx;
        const float* p1 = raw1 + (size_t)q * 24 * HWn + idx;
        float4 t0 = ((const float4*)p0)[0], t1 = ((const float4*)p0)[1];
        float4 u0 = ((const float4*)p1)[0], u1 = ((const float4*)p1)[1];
        r0a.x += t0.x; r0a.y += t0.y; r0a.z += t0.z; r0a.w += t0.w;
        r0b.x += t1.x; r0b.y += t1.y; r0b.z += t1.z; r0b.w += t1.w;
        r1a.x += u0.x; r1a.y += u0.y; r1a.z += u0.z; r1a.w += u0.w;
        r1b.x += u1.x; r1b.y += u1.y; r1b.z += u1.z; r1b.w += u1.w;
    }
    float v0[8] = { sc * r0a.x + c0, sc * r0a.y + c0, sc * r0a.z + c0, sc * r0a.w + c0,
                    sc * r0b.x + c0, sc * r0b.y + c0, sc * r0b.z + c0, sc * r0b.w + c0 };
    float v1[8] = { sc * r1a.x + c1, sc * r1a.y + c1, sc * r1a.z + c1, sc * r1a.w + c1,
                    sc * r1b.x + c1, sc * r1b.y + c1, sc * r1b.z + c1, sc * r1b.w + c1 };
    ((float4*)(v0s + idx))[0] = make_float4(v0[0], v0[1], v0[2], v0[3]);
    ((float4*)(v0s + idx))[1] = make_float4(v0[4], v0[5], v0[6], v0[7]);
    ((float4*)(v1s + idx))[0] = make_float4(v1[0], v1[1], v1[2], v1[3]);
    ((float4*)(v1s + idx))[1] = make_float4(v1[4], v1[5], v1[6], v1[7]);
    float m = -3.4e38f;
#pragma unroll
    for (int i = 0; i < 8; ++i) m = fmaxf(m, v0[i]);
#pragma unroll
    for (int d = 1; d < 64; d <<= 1) m = fmaxf(m, __shfl_xor(m, d, 64));
    __shared__ float wm[4], wsm[4];
    if (lane == 0) wm[wave] = m;
    __syncthreads();
    const float M = fmaxf(fmaxf(wm[0], wm[1]), fmaxf(wm[2], wm[3]));
    float s = 0.f;
#pragma unroll
    for (int i = 0; i < 8; ++i) s += __expf(v0[i] - M);
#pragma unroll
    for (int d = 1; d < 64; d <<= 1) s += __shfl_xor(s, d, 64);
    if (lane == 0) wsm[wave] = s;
    __syncthreads();
    if (tid == 0) {
        float2 o; o.x = M; o.y = wsm[0] + wsm[1] + wsm[2] + wsm[3];
        ms[bc * 8 + ch] = o;
    }
}

// ========== K6: B finalize inline + outer product out[bc,t,s] = A[t]*B[s] ==========
__global__ __launch_bounds__(256) void k6_outer(
    const float* __restrict__ v0s, const float* __restrict__ v1s,
    const float2* __restrict__ ms, const float* __restrict__ A,
    float* __restrict__ out)
{
    const int ch = blockIdx.x;   // 0..15 (chunks of 1024)
    const int bc = blockIdx.y;   // 0..23
    const int tid = threadIdx.x;
    __shared__ float a[Tn];
    if (tid < Tn) a[tid] = A[bc * Tn + tid];
    float M = -3.4e38f;
#pragma unroll
    for (int j = 0; j < 8; ++j) M = fmaxf(M, ms[bc * 8 + j].x);
    float S = 0.f;
#pragma unroll
    for (int j = 0; j < 8; ++j) S += ms[bc * 8 + j].y * __expf(ms[bc * 8 + j].x - M);
    const float invS = __builtin_amdgcn_rcpf(S);
    const int s = ch * 1024 + tid * 4;
    float4 r0 = *(const float4*)(v0s + (size_t)bc * HWn + s);
    float4 r1 = *(const float4*)(v1s + (size_t)bc * HWn + s);
    float4 Bv;
    Bv.x = sqrtf(__expf(r0.x - M) * invS) * r1.x;
    Bv.y = sqrtf(__expf(r0.y - M) * invS) * r1.y;
    Bv.z = sqrtf(__expf(r0.z - M) * invS) * r1.z;
    Bv.w = sqrtf(__expf(r0.w - M) * invS) * r1.w;
    __syncthreads();
    float* op = out + (size_t)bc * Nn + s;
#pragma unroll
    for (int t = 0; t < Tn; ++t) {
        const float av = a[t];
        float4 o; o.x = av * Bv.x; o.y = av * Bv.y; o.z = av * Bv.z; o.w = av * Bv.w;
        *(float4*)(op + (size_t)t * HWn) = o;
    }
}

extern "C" void kernel_launch(void* const* d_in, const int* in_sizes, int n_in,
                              void* d_out, int out_size, void* d_ws, size_t ws_size,
                              hipStream_t stream) {
    const float* x          = (const float*)d_in[0];
    const float* w_spatial  = (const float*)d_in[1];
    const float* b_spatial  = (const float*)d_in[2];
    const float* w_temporal = (const float*)d_in[3];
    const float* b_temporal = (const float*)d_in[4];
    const float* sn_weight  = (const float*)d_in[5];
    const float* sn_bias    = (const float*)d_in[6];
    const float* mean_weight= (const float*)d_in[7];
    const float* var_weight = (const float*)d_in[8];
    const float* w_kv_s     = (const float*)d_in[9];
    const float* w_kv_t     = (const float*)d_in[10];
    float* out = (float*)d_out;
    float* ws  = (float*)d_ws;

    // ws layout (floats)
    float* raw0  = ws;                                   // [NQ][24][HWn] = 3145728
    float* raw1  = raw0 + (size_t)NQ * Bn * Cn * HWn;    // 3145728
    float* pt0p  = raw1 + (size_t)NQ * Bn * Cn * HWn;    // 24*32*128 = 98304
    float* pt1p  = pt0p + (size_t)Bn * Cn * Tn * Hn;     // 98304
    float* ss0p  = pt1p + (size_t)Bn * Cn * Tn * Hn;     // 24*1024 = 24576
    float* ss1p  = ss0p + (size_t)Bn * Cn * Hn * NQ;     // 24576
    float* v0s   = ss1p + (size_t)Bn * Cn * Hn * NQ;     // 24*HWn = 393216
    float* v1s   = v0s + (size_t)Bn * Cn * HWn;          // 393216
    float* kvt0r = v1s + (size_t)Bn * Cn * HWn;          // 768
    float* kvt1r = kvt0r + Bn * Cn * Tn;                 // 768
    float* ssS   = kvt1r + Bn * Cn * Tn;                 // 24
    float* ssSS  = ssS + 24;                             // 24
    float* scale = ssSS + 24;                            // 24
    float* shift = scale + 24;                           // 24
    float* A     = shift + 24;                           // 768
    float* wsum  = A + Bn * Cn * Tn;                     // 4
    float2* ms   = (float2*)(wsum + 4);                  // 192 float2

    k12_conv<<<dim3(Hn / 2, Bn, NQ), 128, 0, stream>>>(x, w_spatial, b_spatial,
                                                       w_temporal, b_temporal,
                                                       w_kv_t, w_kv_s,
                                                       raw0, raw1, pt0p, pt1p, ss0p, ss1p);
    k3a_reduce<<<Bn * Cn + 1, 256, 0, stream>>>(pt0p, pt1p, ss0p, ss1p, w_kv_t, w_kv_s,
                                                kvt0r, kvt1r, ssS, ssSS, wsum);
    k3b_finalize<<<1, 256, 0, stream>>>(kvt0r, kvt1r, ssS, ssSS,
                                        mean_weight, var_weight, sn_weight, sn_bias,
                                        wsum, scale, shift, A);
    k5a_maxsum<<<dim3(8, Bn * Cn), 256, 0, stream>>>(raw0, raw1, scale, shift, wsum,
                                                     v0s, v1s, ms);
    k6_outer<<<dim3(16, Bn * Cn), 256, 0, stream>>>(v0s, v1s, ms, A, out);
}

// Round 10
// 66.203 us; speedup vs baseline: 1.8131x; 1.0935x over previous
//
#include <hip/hip_runtime.h>
#include <hip/hip_bf16.h>

#define Bn 8
#define Cn 3
#define Tn 32
#define Hn 128
#define Wn 128
#define HWn (Hn * Wn)          // 16384
#define Nn (Tn * HWn)          // 524288 elems per (b,c)
#define EPSn 1e-5f
#define NQ 4                   // 4-way t-split (8 output slices each)

__device__ __forceinline__ float silu_f(float v) {
    // fast silu: rcp intrinsic skips the div fixup sequence (absmax headroom ~200x)
    return v * __builtin_amdgcn_rcpf(1.0f + __expf(-v));
}

// ========== K12: fused spatial 3x3 conv + temporal 7-tap conv + all analytics ==========
// CHANNEL-SPLIT waves: wave = one full image row x ONE channel (2 px/thread).
// Register budget is the lever (cliff bites AT vgpr=64 — r8/r9 evidence): per-thread
// state = ring 7xfloat2 (14) + a0/a1 (4) + ps/pq (2) + k0v/k1v (4) ~= 50 VGPR.
// Block = 256 threads = 4 waves = 4 adjacent rows of one (b,c,qtr). No LDS, no barriers
// in the t-loop. Horizontal halo via __shfl_up/down, vertical via direct row loads.
// t split in 4 quarters (8 outputs, <=13 slices -> 1.6x spatial redundancy).
// Outputs:
//   raw0/raw1[qtr][bc][s]     = partial sum_t wks{0,1}[t]*g    (kv_s contraction)
//   pt0p/pt1p[bc][t][row]     = per-row  sum_s g*wkt{0,1}[s]   (kv_t contraction)
//   ss0p/ss1p[bc][row*NQ+qtr] = per-wave {sum g, sum g^2}      (SwitchNorm stats)
template<int QTR>
__device__ __forceinline__ void k12_body(
    const float* __restrict__ x, const float* __restrict__ wsp,
    const float* __restrict__ bsp, const float* __restrict__ wtp,
    const float* __restrict__ btp, const float* __restrict__ wkt,
    const float* __restrict__ wks,
    float* __restrict__ raw0, float* __restrict__ raw1,
    float* __restrict__ pt0p, float* __restrict__ pt1p,
    float* __restrict__ ss0p, float* __restrict__ ss1p)
{
    constexpr int O0 = QTR * 8;
    constexpr int O1 = O0 + 8;
    constexpr int SLO = (O0 - 3 < 0) ? 0 : (O0 - 3);
    constexpr int SHI = (O1 + 2 > Tn - 1) ? (Tn - 1) : (O1 + 2);

    const int tid = threadIdx.x;
    const int lane = tid & 63;
    const int wave = tid >> 6;
    const int row = blockIdx.x * 4 + wave;   // 0..127
    const int bc  = blockIdx.y;              // 0..23
    const int b = bc / 3, c = bc % 3;
    const int col = lane * 2;

    // own-channel uniform weights -> scalar regs
    float wsp_r[9], wt_r[7];
#pragma unroll
    for (int i = 0; i < 9; ++i) wsp_r[i] = wsp[c * 9 + i];
    const float bsp_r = bsp[c];
#pragma unroll
    for (int i = 0; i < 7; ++i) wt_r[i] = wtp[c * 7 + i];
    const float bt_r = btp[c];

    const float* xb = x + (size_t)b * Nn + (size_t)row * Wn + col;
    const bool upok = row > 0, dnok = row < Hn - 1;

    const float2 k0v = *(const float2*)(wkt + row * Wn + col);
    const float2 k1v = *(const float2*)(wkt + HWn + row * Wn + col);

    float2 ring[7];
    float2 a0 = make_float2(0.f, 0.f), a1 = make_float2(0.f, 0.f);
    float ps = 0.f, pq = 0.f;

#pragma unroll
    for (int tt = SLO; tt <= SHI + 3; ++tt) {
        if (tt <= SHI) {
            const float* xsl = xb + (size_t)tt * HWn;
            float2 xm = upok ? *(const float2*)(xsl - Wn) : make_float2(0.f, 0.f);
            float2 xc = *(const float2*)(xsl);
            float2 xp = dnok ? *(const float2*)(xsl + Wn) : make_float2(0.f, 0.f);
            float xv[3][4];
            {
                float lu, rd;
                lu = __shfl_up(xm.y, 1);  rd = __shfl_down(xm.x, 1);
                xv[0][0] = (lane == 0) ? 0.f : lu; xv[0][1] = xm.x; xv[0][2] = xm.y;
                xv[0][3] = (lane == 63) ? 0.f : rd;
                lu = __shfl_up(xc.y, 1);  rd = __shfl_down(xc.x, 1);
                xv[1][0] = (lane == 0) ? 0.f : lu; xv[1][1] = xc.x; xv[1][2] = xc.y;
                xv[1][3] = (lane == 63) ? 0.f : rd;
                lu = __shfl_up(xp.y, 1);  rd = __shfl_down(xp.x, 1);
                xv[2][0] = (lane == 0) ? 0.f : lu; xv[2][1] = xp.x; xv[2][2] = xp.y;
                xv[2][3] = (lane == 63) ? 0.f : rd;
            }
            float s0 = bsp_r, s1 = bsp_r;
#pragma unroll
            for (int i = 0; i < 3; ++i) {
#pragma unroll
                for (int j = 0; j < 3; ++j) {
                    const float wv = wsp_r[i * 3 + j];
                    s0 += wv * xv[i][j];
                    s1 += wv * xv[i][j + 1];
                }
            }
            ring[tt % 7].x = silu_f(s0);
            ring[tt % 7].y = silu_f(s1);
        }
        const int to = tt - 3;
        if (to >= O0 && to < O1) {          // compile-time pruned per unrolled iter
            float t0 = bt_r, t1 = bt_r;
#pragma unroll
            for (int k = 0; k < 7; ++k) {
                const int ts = to + k - 3;
                if (ts >= 0 && ts < Tn) {   // compile-time
                    const float wv = wt_r[k];
                    t0 += wv * ring[ts % 7].x;
                    t1 += wv * ring[ts % 7].y;
                }
            }
            const float g0 = silu_f(silu_f(t0));
            const float g1 = silu_f(silu_f(t1));
            const float wk0 = wks[to];      // uniform scalar loads
            const float wk1 = wks[Tn + to];
            a0.x += wk0 * g0; a0.y += wk0 * g1;
            a1.x += wk1 * g0; a1.y += wk1 * g1;
            ps += g0 + g1;
            pq += g0 * g0 + g1 * g1;
            // 2-value packed wave reduce: 3 xor stages in 8-groups, select by parity,
            // 3 more stages across groups -> lane0 = total p0, lane1 = total p1.
            float p0 = k0v.x * g0 + k0v.y * g1;
            float p1 = k1v.x * g0 + k1v.y * g1;
            p0 += __shfl_xor(p0, 1, 64); p0 += __shfl_xor(p0, 2, 64); p0 += __shfl_xor(p0, 4, 64);
            p1 += __shfl_xor(p1, 1, 64); p1 += __shfl_xor(p1, 2, 64); p1 += __shfl_xor(p1, 4, 64);
            float r = (lane & 1) ? p1 : p0;
            r += __shfl_xor(r, 8, 64);
            r += __shfl_xor(r, 16, 64);
            r += __shfl_xor(r, 32, 64);
            if (lane < 2) {
                float* dst = lane ? pt1p : pt0p;
                dst[((size_t)bc * Tn + to) * Hn + row] = r;
            }
        }
    }

    // --- wave-reduce ps/pq via the same packed trick ---
    {
        float p0 = ps, p1 = pq;
        p0 += __shfl_xor(p0, 1, 64); p0 += __shfl_xor(p0, 2, 64); p0 += __shfl_xor(p0, 4, 64);
        p1 += __shfl_xor(p1, 1, 64); p1 += __shfl_xor(p1, 2, 64); p1 += __shfl_xor(p1, 4, 64);
        float r = (lane & 1) ? p1 : p0;
        r += __shfl_xor(r, 8, 64);
        r += __shfl_xor(r, 16, 64);
        r += __shfl_xor(r, 32, 64);
        if (lane == 0) ss0p[(size_t)bc * (Hn * NQ) + row * NQ + QTR] = r;
        if (lane == 1) ss1p[(size_t)bc * (Hn * NQ) + row * NQ + QTR] = r;
    }
    // --- raw kv_s stores (per-quarter buffers) ---
    {
        const size_t off = (size_t)(QTR * 24 + bc) * HWn + (size_t)row * Wn + col;
        *(float2*)(raw0 + off) = a0;
        *(float2*)(raw1 + off) = a1;
    }
}

__global__ __launch_bounds__(256) void k12_conv(
    const float* __restrict__ x, const float* __restrict__ wsp,
    const float* __restrict__ bsp, const float* __restrict__ wtp,
    const float* __restrict__ btp, const float* __restrict__ wkt,
    const float* __restrict__ wks,
    float* __restrict__ raw0, float* __restrict__ raw1,
    float* __restrict__ pt0p, float* __restrict__ pt1p,
    float* __restrict__ ss0p, float* __restrict__ ss1p)
{
    switch (blockIdx.z) {
    case 0: k12_body<0>(x, wsp, bsp, wtp, btp, wkt, wks, raw0, raw1, pt0p, pt1p, ss0p, ss1p); break;
    case 1: k12_body<1>(x, wsp, bsp, wtp, btp, wkt, wks, raw0, raw1, pt0p, pt1p, ss0p, ss1p); break;
    case 2: k12_body<2>(x, wsp, bsp, wtp, btp, wkt, wks, raw0, raw1, pt0p, pt1p, ss0p, ss1p); break;
    default: k12_body<3>(x, wsp, bsp, wtp, btp, wkt, wks, raw0, raw1, pt0p, pt1p, ss0p, ss1p); break;
    }
}

// ========== K3a: parallel reduction of pt/ss partials + wkt/wks sums ==========
// blocks 0..23: per-bc reduce; block 24: weight sums.
__global__ __launch_bounds__(256) void k3a_reduce(
    const float* __restrict__ pt0p, const float* __restrict__ pt1p,
    const float* __restrict__ ss0p, const float* __restrict__ ss1p,
    const float* __restrict__ wkt, const float* __restrict__ wks,
    float* __restrict__ kvt0r, float* __restrict__ kvt1r,
    float* __restrict__ ssS, float* __restrict__ ssSS, float* __restrict__ wsum)
{
    const int blk = blockIdx.x;
    const int tid = threadIdx.x;
    if (blk < Bn * Cn) {
        // pt reduce: 32 t-rows of 128; 8 threads per t
        const int t = tid >> 3, g = tid & 7;
        const float4* p0 = (const float4*)(pt0p + ((size_t)blk * Tn + t) * Hn) + g * 4;
        const float4* p1 = (const float4*)(pt1p + ((size_t)blk * Tn + t) * Hn) + g * 4;
        float4 A0 = p0[0], A1 = p0[1], A2 = p0[2], A3 = p0[3];
        float4 B0 = p1[0], B1 = p1[1], B2 = p1[2], B3 = p1[3];
        float s0 = ((A0.x + A0.y) + (A0.z + A0.w)) + ((A1.x + A1.y) + (A1.z + A1.w))
                 + ((A2.x + A2.y) + (A2.z + A2.w)) + ((A3.x + A3.y) + (A3.z + A3.w));
        float s1 = ((B0.x + B0.y) + (B0.z + B0.w)) + ((B1.x + B1.y) + (B1.z + B1.w))
                 + ((B2.x + B2.y) + (B2.z + B2.w)) + ((B3.x + B3.y) + (B3.z + B3.w));
        s0 += __shfl_xor(s0, 1, 64); s0 += __shfl_xor(s0, 2, 64); s0 += __shfl_xor(s0, 4, 64);
        s1 += __shfl_xor(s1, 1, 64); s1 += __shfl_xor(s1, 2, 64); s1 += __shfl_xor(s1, 4, 64);
        if (g == 0) { kvt0r[blk * Tn + t] = s0; kvt1r[blk * Tn + t] = s1; }
        // ss reduce: 512 floats each array (128 float4)
        const float4* q0 = (const float4*)(ss0p + (size_t)blk * (Hn * NQ));
        const float4* q1 = (const float4*)(ss1p + (size_t)blk * (Hn * NQ));
        float a = 0.f, bb = 0.f;
        if (tid < Hn * NQ / 4) {
            float4 a4 = q0[tid], b4 = q1[tid];
            a = (a4.x + a4.y) + (a4.z + a4.w);
            bb = (b4.x + b4.y) + (b4.z + b4.w);
        }
        __shared__ float r0[256], r1[256];
        r0[tid] = a; r1[tid] = bb;
        __syncthreads();
        for (int off = 128; off > 0; off >>= 1) {
            if (tid < off) { r0[tid] += r0[tid + off]; r1[tid] += r1[tid + off]; }
            __syncthreads();
        }
        if (tid == 0) { ssS[blk] = r0[0]; ssSS[blk] = r1[0]; }
    } else {
        // wkt sums (2 x 16384) and wks sums (2 x 32)
        const float4* w0 = (const float4*)wkt;
        const float4* w1 = (const float4*)(wkt + HWn);
        float l0 = 0.f, l1 = 0.f;
        for (int i = tid; i < HWn / 4; i += 256) {
            float4 t0 = w0[i], t1 = w1[i];
            l0 += (t0.x + t0.y) + (t0.z + t0.w);
            l1 += (t1.x + t1.y) + (t1.z + t1.w);
        }
        __shared__ float r0[256], r1[256];
        r0[tid] = l0; r1[tid] = l1;
        __syncthreads();
        for (int off = 128; off > 0; off >>= 1) {
            if (tid < off) { r0[tid] += r0[tid + off]; r1[tid] += r1[tid + off]; }
            __syncthreads();
        }
        if (tid == 0) { wsum[0] = r0[0]; wsum[1] = r1[0]; }
        if (tid < 64) {
            float v = wks[tid];   // lanes 0..31 hold wks0, 32..63 hold wks1
            v += __shfl_xor(v, 1, 64); v += __shfl_xor(v, 2, 64);
            v += __shfl_xor(v, 4, 64); v += __shfl_xor(v, 8, 64);
            v += __shfl_xor(v, 16, 64);
            if (tid == 0) wsum[2] = v;
            if (tid == 32) wsum[3] = v;
        }
    }
}

// ========== K3b: SwitchNorm stats + kv_t softmax -> A, scale/shift (tiny) ==========
__global__ __launch_bounds__(256) void k3b_finalize(
    const float* __restrict__ kvt0r, const float* __restrict__ kvt1r,
    const float* __restrict__ ssS, const float* __restrict__ ssSS,
    const float* __restrict__ mean_w, const float* __restrict__ var_w,
    const float* __restrict__ snw, const float* __restrict__ snb,
    const float* __restrict__ wsum,
    float* __restrict__ scale, float* __restrict__ shift, float* __restrict__ A)
{
    const int tid = threadIdx.x;
    __shared__ float kvt0[Bn * Cn * Tn], kvt1[Bn * Cn * Tn];
    __shared__ float sW[4];
    for (int i = tid; i < Bn * Cn * Tn; i += 256) { kvt0[i] = kvt0r[i]; kvt1[i] = kvt1r[i]; }
    if (tid < 4) sW[tid] = wsum[tid];
    __shared__ float sh_mean[24], sh_var[24], sh_temp[24];
    __shared__ float sh_mln[8], sh_vln[8], sh_mbn[3], sh_vbn[3];
    __shared__ float sh_mw[3], sh_vw[3];
    __shared__ float sh_scale[24], sh_shift[24];
    if (tid < 24) {
        float S = ssS[tid], SS = ssSS[tid];
        const float Nf = (float)Nn;
        float mean = S / Nf;
        float var = (SS - S * mean) / (Nf - 1.0f);   // unbiased (ddof=1)
        sh_mean[tid] = mean; sh_var[tid] = var; sh_temp[tid] = var + mean * mean;
    }
    __syncthreads();
    if (tid == 0) {
        for (int b = 0; b < Bn; ++b) {
            float m = 0.f, tp = 0.f;
            for (int c = 0; c < Cn; ++c) { m += sh_mean[b * 3 + c]; tp += sh_temp[b * 3 + c]; }
            m *= (1.0f / 3.0f); tp *= (1.0f / 3.0f);
            sh_mln[b] = m; sh_vln[b] = tp - m * m;
        }
        for (int c = 0; c < Cn; ++c) {
            float m = 0.f, tp = 0.f;
            for (int b = 0; b < Bn; ++b) { m += sh_mean[b * 3 + c]; tp += sh_temp[b * 3 + c]; }
            m *= 0.125f; tp *= 0.125f;
            sh_mbn[c] = m; sh_vbn[c] = tp - m * m;
        }
        {
            float m0 = mean_w[0], m1 = mean_w[1], m2 = mean_w[2];
            float mm = fmaxf(m0, fmaxf(m1, m2));
            float e0 = __expf(m0 - mm), e1 = __expf(m1 - mm), e2 = __expf(m2 - mm);
            float inv = 1.0f / (e0 + e1 + e2);
            sh_mw[0] = e0 * inv; sh_mw[1] = e1 * inv; sh_mw[2] = e2 * inv;
        }
        {
            float v0 = var_w[0], v1 = var_w[1], v2 = var_w[2];
            float vm = fmaxf(v0, fmaxf(v1, v2));
            float e0 = __expf(v0 - vm), e1 = __expf(v1 - vm), e2 = __expf(v2 - vm);
            float inv = 1.0f / (e0 + e1 + e2);
            sh_vw[0] = e0 * inv; sh_vw[1] = e1 * inv; sh_vw[2] = e2 * inv;
        }
    }
    __syncthreads();
    if (tid < 24) {
        int b = tid / 3, c = tid % 3;
        float mean = sh_mw[0] * sh_mean[tid] + sh_mw[1] * sh_mln[b] + sh_mw[2] * sh_mbn[c];
        float var  = sh_vw[0] * sh_var[tid]  + sh_vw[1] * sh_vln[b] + sh_vw[2] * sh_vbn[c];
        float inv = 1.0f / sqrtf(var + EPSn);
        float sc = inv * snw[c];
        float sf = snb[c] - mean * sc;
        sh_scale[tid] = sc; sh_shift[tid] = sf;
        scale[tid] = sc; shift[tid] = sf;
    }
    __syncthreads();
    for (int i = tid; i < Bn * Cn * Tn; i += 256) {
        int bc = i >> 5;
        kvt0[i] = sh_scale[bc] * kvt0[i] + sh_shift[bc] * sW[0];
        kvt1[i] = sh_scale[bc] * kvt1[i] + sh_shift[bc] * sW[1];
    }
    __syncthreads();
    if (tid < 24) {
        float m = -3.4e38f;
        for (int t = 0; t < Tn; ++t) m = fmaxf(m, kvt0[tid * Tn + t]);
        float se = 0.f;
        for (int t = 0; t < Tn; ++t) se += __expf(kvt0[tid * Tn + t] - m);
        float inv = 1.0f / se;
        for (int t = 0; t < Tn; ++t)
            A[tid * Tn + t] = sqrtf(__expf(kvt0[tid * Tn + t] - m) * inv) * kvt1[tid * Tn + t];
    }
}

// ========== K5a: reduce raw quarters + affine; chunk max/expsum -> v0s/v1s, ms ==========
__global__ __launch_bounds__(256) void k5a_maxsum(
    const float* __restrict__ raw0, const float* __restrict__ raw1,
    const float* __restrict__ scale, const float* __restrict__ shift,
    const float* __restrict__ wsum, float* __restrict__ v0s,
    float* __restrict__ v1s, float2* __restrict__ ms)
{
    const int ch = blockIdx.x;   // 0..7 (chunks of 2048)
    const int bc = blockIdx.y;   // 0..23
    const int tid = threadIdx.x, lane = tid & 63, wave = tid >> 6;
    const float sc = scale[bc], sf = shift[bc];
    const float c0 = sf * wsum[2], c1 = sf * wsum[3];
    const size_t idx = (size_t)bc * HWn + ch * 2048 + tid * 8;
    float4 r0a = make_float4(0.f, 0.f, 0.f, 0.f), r0b = r0a, r1a = r0a, r1b = r0a;
#pragma unroll
    for (int q = 0; q < NQ; ++q) {
        const float* p0 = raw0 + (size_t)q * 24 * HWn + idx;
        const float* p1 = raw1 + (size_t)q * 24 * HWn + idx;
        float4 t0 = ((const float4*)p0)[0], t1 = ((const float4*)p0)[1];
        float4 u0 = ((const float4*)p1)[0], u1 = ((const float4*)p1)[1];
        r0a.x += t0.x; r0a.y += t0.y; r0a.z += t0.z; r0a.w += t0.w;
        r0b.x += t1.x; r0b.y += t1.y; r0b.z += t1.z; r0b.w += t1.w;
        r1a.x += u0.x; r1a.y += u0.y; r1a.z += u0.z; r1a.w += u0.w;
        r1b.x += u1.x; r1b.y += u1.y; r1b.z += u1.z; r1b.w += u1.w;
    }
    float v0[8] = { sc * r0a.x + c0, sc * r0a.y + c0, sc * r0a.z + c0, sc * r0a.w + c0,
                    sc * r0b.x + c0, sc * r0b.y + c0, sc * r0b.z + c0, sc * r0b.w + c0 };
    float v1[8] = { sc * r1a.x + c1, sc * r1a.y + c1, sc * r1a.z + c1, sc * r1a.w + c1,
                    sc * r1b.x + c1, sc * r1b.y + c1, sc * r1b.z + c1, sc * r1b.w + c1 };
    ((float4*)(v0s + idx))[0] = make_float4(v0[0], v0[1], v0[2], v0[3]);
    ((float4*)(v0s + idx))[1] = make_float4(v0[4], v0[5], v0[6], v0[7]);
    ((float4*)(v1s + idx))[0] = make_float4(v1[0], v1[1], v1[2], v1[3]);
    ((float4*)(v1s + idx))[1] = make_float4(v1[4], v1[5], v1[6], v1[7]);
    float m = -3.4e38f;
#pragma unroll
    for (int i = 0; i < 8; ++i) m = fmaxf(m, v0[i]);
#pragma unroll
    for (int d = 1; d < 64; d <<= 1) m = fmaxf(m, __shfl_xor(m, d, 64));
    __shared__ float wm[4], wsm[4];
    if (lane == 0) wm[wave] = m;
    __syncthreads();
    const float M = fmaxf(fmaxf(wm[0], wm[1]), fmaxf(wm[2], wm[3]));
    float s = 0.f;
#pragma unroll
    for (int i = 0; i < 8; ++i) s += __expf(v0[i] - M);
#pragma unroll
    for (int d = 1; d < 64; d <<= 1) s += __shfl_xor(s, d, 64);
    if (lane == 0) wsm[wave] = s;
    __syncthreads();
    if (tid == 0) {
        float2 o; o.x = M; o.y = wsm[0] + wsm[1] + wsm[2] + wsm[3];
        ms[bc * 8 + ch] = o;
    }
}

// ========== K6: B finalize inline + outer product out[bc,t,s] = A[t]*B[s] ==========
__global__ __launch_bounds__(256) void k6_outer(
    const float* __restrict__ v0s, const float* __restrict__ v1s,
    const float2* __restrict__ ms, const float* __restrict__ A,
    float* __restrict__ out)
{
    const int ch = blockIdx.x;   // 0..15 (chunks of 1024)
    const int bc = blockIdx.y;   // 0..23
    const int tid = threadIdx.x;
    __shared__ float a[Tn];
    if (tid < Tn) a[tid] = A[bc * Tn + tid];
    float M = -3.4e38f;
#pragma unroll
    for (int j = 0; j < 8; ++j) M = fmaxf(M, ms[bc * 8 + j].x);
    float S = 0.f;
#pragma unroll
    for (int j = 0; j < 8; ++j) S += ms[bc * 8 + j].y * __expf(ms[bc * 8 + j].x - M);
    const float invS = __builtin_amdgcn_rcpf(S);
    const int s = ch * 1024 + tid * 4;
    float4 r0 = *(const float4*)(v0s + (size_t)bc * HWn + s);
    float4 r1 = *(const float4*)(v1s + (size_t)bc * HWn + s);
    float4 Bv;
    Bv.x = sqrtf(__expf(r0.x - M) * invS) * r1.x;
    Bv.y = sqrtf(__expf(r0.y - M) * invS) * r1.y;
    Bv.z = sqrtf(__expf(r0.z - M) * invS) * r1.z;
    Bv.w = sqrtf(__expf(r0.w - M) * invS) * r1.w;
    __syncthreads();
    float* op = out + (size_t)bc * Nn + s;
#pragma unroll
    for (int t = 0; t < Tn; ++t) {
        const float av = a[t];
        float4 o; o.x = av * Bv.x; o.y = av * Bv.y; o.z = av * Bv.z; o.w = av * Bv.w;
        *(float4*)(op + (size_t)t * HWn) = o;
    }
}

extern "C" void kernel_launch(void* const* d_in, const int* in_sizes, int n_in,
                              void* d_out, int out_size, void* d_ws, size_t ws_size,
                              hipStream_t stream) {
    const float* x          = (const float*)d_in[0];
    const float* w_spatial  = (const float*)d_in[1];
    const float* b_spatial  = (const float*)d_in[2];
    const float* w_temporal = (const float*)d_in[3];
    const float* b_temporal = (const float*)d_in[4];
    const float* sn_weight  = (const float*)d_in[5];
    const float* sn_bias    = (const float*)d_in[6];
    const float* mean_weight= (const float*)d_in[7];
    const float* var_weight = (const float*)d_in[8];
    const float* w_kv_s     = (const float*)d_in[9];
    const float* w_kv_t     = (const float*)d_in[10];
    float* out = (float*)d_out;
    float* ws  = (float*)d_ws;

    // ws layout (floats)
    float* raw0  = ws;                                   // [NQ][24][HWn] = 1572864
    float* raw1  = raw0 + (size_t)NQ * Bn * Cn * HWn;    // 1572864
    float* pt0p  = raw1 + (size_t)NQ * Bn * Cn * HWn;    // 24*32*128 = 98304
    float* pt1p  = pt0p + (size_t)Bn * Cn * Tn * Hn;     // 98304
    float* ss0p  = pt1p + (size_t)Bn * Cn * Tn * Hn;     // 24*512 = 12288
    float* ss1p  = ss0p + (size_t)Bn * Cn * Hn * NQ;     // 12288
    float* v0s   = ss1p + (size_t)Bn * Cn * Hn * NQ;     // 24*HWn = 393216
    float* v1s   = v0s + (size_t)Bn * Cn * HWn;          // 393216
    float* kvt0r = v1s + (size_t)Bn * Cn * HWn;          // 768
    float* kvt1r = kvt0r + Bn * Cn * Tn;                 // 768
    float* ssS   = kvt1r + Bn * Cn * Tn;                 // 24
    float* ssSS  = ssS + 24;                             // 24
    float* scale = ssSS + 24;                            // 24
    float* shift = scale + 24;                           // 24
    float* A     = shift + 24;                           // 768
    float* wsum  = A + Bn * Cn * Tn;                     // 4
    float2* ms   = (float2*)(wsum + 4);                  // 192 float2

    k12_conv<<<dim3(Hn / 4, Bn * Cn, NQ), 256, 0, stream>>>(x, w_spatial, b_spatial,
                                                            w_temporal, b_temporal,
                                                            w_kv_t, w_kv_s,
                                                            raw0, raw1, pt0p, pt1p,
                                                            ss0p, ss1p);
    k3a_reduce<<<Bn * Cn + 1, 256, 0, stream>>>(pt0p, pt1p, ss0p, ss1p, w_kv_t, w_kv_s,
                                                kvt0r, kvt1r, ssS, ssSS, wsum);
    k3b_finalize<<<1, 256, 0, stream>>>(kvt0r, kvt1r, ssS, ssSS,
                                        mean_weight, var_weight, sn_weight, sn_bias,
                                        wsum, scale, shift, A);
    k5a_maxsum<<<dim3(8, Bn * Cn), 256, 0, stream>>>(raw0, raw1, scale, shift, wsum,
                                                     v0s, v1s, ms);
    k6_outer<<<dim3(16, Bn * Cn), 256, 0, stream>>>(v0s, v1s, ms, A, out);
}